// Round 1
// baseline (253.266 us; speedup 1.0000x reference)
//
#include <hip/hip_runtime.h>

typedef __attribute__((ext_vector_type(8))) short short8;
typedef __attribute__((ext_vector_type(4))) float f32x4;

union BF8 { short8 v; unsigned long long q[2]; };

__device__ __forceinline__ unsigned short f2bf(float f) {
    unsigned int u = __float_as_uint(f);
    u += 0x7fffu + ((u >> 16) & 1u);
    return (unsigned short)(u >> 16);
}

// ---------------------------------------------------------------------------
// Kernel 1: per coefficient slice n (5 blocks):
//   A = 0.5*(W[:,:,n] - W[:,:,n]^T); 50 power iterations; sigma; An = A/sigma;
//   Fm = sum_{t=1..10} An^t / t!  (+ I); write Fm[n][i][j] f32 to ws.
// ---------------------------------------------------------------------------
__global__ __launch_bounds__(512) void fm_kernel(const float* __restrict__ W,
                                                 const float* __restrict__ u0,
                                                 float* __restrict__ FmOut) {
    const int n = blockIdx.x;   // 0..4
    const int t = threadIdx.x;  // 0..511
    __shared__ float A[64][65];
    __shared__ float Bu1[64][65];
    __shared__ float Bu2[64][65];
    __shared__ float uS[64], vS[64];
    __shared__ float sigS;

    // stage A (skew-symmetric part), W layout (C,C,5): W[i][j][n]
    {
        const int i = t >> 3;
        const int j0 = (t & 7) * 8;
#pragma unroll
        for (int k = 0; k < 8; ++k) {
            const int j = j0 + k;
            const float wij = W[(i * 64 + j) * 5 + n];
            const float wji = W[(j * 64 + i) * 5 + n];
            A[i][j] = 0.5f * (wij - wji);
        }
    }
    __syncthreads();

    // power iteration on wave 0 only (lane = i or j index)
    if (t < 64) {
        const int lane = t;
        float u = u0[n * 64 + lane];
        float s0 = u * u;
#pragma unroll
        for (int m = 1; m < 64; m <<= 1) s0 += __shfl_xor(s0, m);
        u = u / (sqrtf(s0) + 1e-12f);
        uS[lane] = u;
        for (int it = 0; it < 50; ++it) {
            // v_i = l2n( sum_j A[i][j] u_j )
            float acc = 0.0f;
            for (int j = 0; j < 64; ++j) acc += A[lane][j] * uS[j];
            float ss = acc * acc;
#pragma unroll
            for (int m = 1; m < 64; m <<= 1) ss += __shfl_xor(ss, m);
            vS[lane] = acc / (sqrtf(ss) + 1e-12f);
            // u_j = l2n( sum_i A[i][j] v_i )
            float acc2 = 0.0f;
            for (int i = 0; i < 64; ++i) acc2 += A[i][lane] * vS[i];
            float s2 = acc2 * acc2;
#pragma unroll
            for (int m = 1; m < 64; m <<= 1) s2 += __shfl_xor(s2, m);
            uS[lane] = acc2 / (sqrtf(s2) + 1e-12f);
        }
        // sigma = sum_ij A[i][j] v_i u_j  (with final u, v)
        float wsum = 0.0f;
        for (int j = 0; j < 64; ++j) wsum += A[lane][j] * uS[j];
        float part = vS[lane] * wsum;
#pragma unroll
        for (int m = 1; m < 64; m <<= 1) part += __shfl_xor(part, m);
        if (lane == 0) sigS = part;
    }
    __syncthreads();

    const float sig = sigS;
    {
        const int i = t >> 3;
        const int j0 = (t & 7) * 8;
#pragma unroll
        for (int k = 0; k < 8; ++k) A[i][j0 + k] = A[i][j0 + k] / sig;  // An in place
    }
    __syncthreads();

    // Taylor series: fm = An; curr = An; for term 2..10: curr = curr@An/term; fm += curr
    const int r = t >> 3;
    const int c0 = (t & 7) * 8;
    float fm[8];
#pragma unroll
    for (int k = 0; k < 8; ++k) {
        const float an = A[r][c0 + k];
        fm[k] = an;
        Bu1[r][c0 + k] = an;
    }
    __syncthreads();

    float* curp = &Bu1[0][0];
    float* nxtp = &Bu2[0][0];
    for (int term = 2; term <= 10; ++term) {
        float nx[8];
#pragma unroll
        for (int k = 0; k < 8; ++k) nx[k] = 0.0f;
        for (int j = 0; j < 64; ++j) {
            const float crj = curp[r * 65 + j];
            const float* arow = &A[j][c0];
#pragma unroll
            for (int k = 0; k < 8; ++k) nx[k] += crj * arow[k];
        }
        const float ft = (float)term;
#pragma unroll
        for (int k = 0; k < 8; ++k) {
            nx[k] = nx[k] / ft;
            nxtp[r * 65 + c0 + k] = nx[k];
            fm[k] += nx[k];
        }
        __syncthreads();
        float* tmp = curp; curp = nxtp; nxtp = tmp;
    }
#pragma unroll
    for (int k = 0; k < 8; ++k)
        FmOut[n * 4096 + r * 64 + c0 + k] = fm[k] + ((r == (c0 + k)) ? 1.0f : 0.0f);
}

// ---------------------------------------------------------------------------
// Kernel 2: build folded GEMM weight Wt[m=(a*3+b)*64+o][kap=(al*3+be)*64+i] bf16
//   K[o][i][u][v] = (1/9) sum_{p,q} Fm[IDX[p][q]][o][i] * c((p*u+q*v)%3),
//   c(0)=1, else -0.5 (real ifft2 of 3x3);  Wt = K[o][i][(al-a+1)%3][(be-b+1)%3]
// ---------------------------------------------------------------------------
__global__ __launch_bounds__(256) void wbuild_kernel(const float* __restrict__ Fm,
                                                     unsigned short* __restrict__ Wt) {
    const int tg = blockIdx.x * 256 + threadIdx.x;  // 0..4095
    const int o = tg >> 6;
    const int i = tg & 63;
    float f[5];
#pragma unroll
    for (int nn = 0; nn < 5; ++nn) f[nn] = Fm[nn * 4096 + o * 64 + i];
    const int idx[3][3] = {{0, 1, 1}, {2, 3, 4}, {2, 4, 3}};
    float Kk[3][3];
#pragma unroll
    for (int u = 0; u < 3; ++u) {
#pragma unroll
        for (int v = 0; v < 3; ++v) {
            float s = 0.0f;
#pragma unroll
            for (int p = 0; p < 3; ++p) {
#pragma unroll
                for (int q = 0; q < 3; ++q) {
                    const int m = (p * u + q * v) % 3;
                    s += f[idx[p][q]] * ((m == 0) ? 1.0f : -0.5f);
                }
            }
            Kk[u][v] = s * (1.0f / 9.0f);
        }
    }
#pragma unroll
    for (int a = 0; a < 3; ++a) {
#pragma unroll
        for (int b = 0; b < 3; ++b) {
#pragma unroll
            for (int al = 0; al < 3; ++al) {
#pragma unroll
                for (int be = 0; be < 3; ++be) {
                    const int kh = (al - a + 4) % 3;  // (al-a+1) mod 3
                    const int kw = (be - b + 4) % 3;
                    Wt[((a * 3 + b) * 64 + o) * 576 + (al * 3 + be) * 64 + i] =
                        f2bf(Kk[kh][kw]);
                }
            }
        }
    }
}

// ---------------------------------------------------------------------------
// Kernel 3: folded conv as GEMM.  Z[m][p] = sum_kap Wt[m][kap] * X[kap][p]
//   m = (a*3+b)*64+o (576 total), p = (n,h0,w0), kap = (al*3+be)*64+i.
//   Block: 64 positions (one n,h0; all w0) x 192 outs (blockIdx.y of 3).
//   4 waves, each 48 m-rows x 64 positions (3x4 frags of 16x16), K-step 32.
// ---------------------------------------------------------------------------
__global__ __launch_bounds__(256) void gemm_kernel(const float* __restrict__ x,
                                                   const unsigned short* __restrict__ Wt,
                                                   const float* __restrict__ bias,
                                                   float* __restrict__ out) {
    __shared__ unsigned short Xs[64][36];  // [position w0][local kap], pitch 36 (72B)
    const int t = threadIdx.x;
    const int lane = t & 63;
    const int wv = t >> 6;  // wave 0..3
    const int pblk = blockIdx.x;
    const int mg = blockIdx.y;
    const int n = pblk >> 6;
    const int h0 = pblk & 63;
    const int wave_m0 = mg * 192 + wv * 48;
    const int lm = lane & 15;
    const int lg = lane >> 4;

    f32x4 acc[3][4] = {};

    const float* xb = x + n * 64 * 36864;  // image n, x[n][i][h][w]
    const int w0s = t & 63;
    const int kq = (t >> 6) * 8;  // this wave stages local kap rows kq..kq+7

    for (int c = 0; c < 18; ++c) {
        const int ab = c >> 1;          // al*3+be
        const int al = ab / 3;
        const int be = ab % 3;
        const int ih = (c & 1) * 32;    // channel half
        const int base = ih * 36864 + (h0 + 64 * al) * 192 + 64 * be + w0s;
#pragma unroll
        for (int s = 0; s < 8; ++s) {
            const int kp = kq + s;  // local kap 0..31
            Xs[w0s][kp] = f2bf(xb[base + kp * 36864]);
        }
        __syncthreads();

        const int kb = c * 32 + lg * 8;  // global kap base for this lane's A frag
        short8 af[3];
#pragma unroll
        for (int mf = 0; mf < 3; ++mf)
            af[mf] = *(const short8*)(Wt + (wave_m0 + mf * 16 + lm) * 576 + kb);
        short8 bf[4];
#pragma unroll
        for (int pf = 0; pf < 4; ++pf) {
            const unsigned long long* s8 =
                (const unsigned long long*)(&Xs[pf * 16 + lm][lg * 8]);
            BF8 u;
            u.q[0] = s8[0];
            u.q[1] = s8[1];
            bf[pf] = u.v;
        }
#pragma unroll
        for (int mf = 0; mf < 3; ++mf) {
#pragma unroll
            for (int pf = 0; pf < 4; ++pf) {
                acc[mf][pf] = __builtin_amdgcn_mfma_f32_16x16x32_bf16(
                    af[mf], bf[pf], acc[mf][pf], 0, 0, 0);
            }
        }
        __syncthreads();
    }

    // epilogue: D row = m (lg*4+r within frag), col = w0 (lm); + bias
#pragma unroll
    for (int mf = 0; mf < 3; ++mf) {
#pragma unroll
        for (int r = 0; r < 4; ++r) {
            const int m = wave_m0 + mf * 16 + lg * 4 + r;
            const int o = m & 63;
            const int ab2 = m >> 6;
            const float bo = bias[o];
            const int rowoff =
                ((n * 64 + o) * 192 + (h0 + 64 * (ab2 / 3))) * 192 + 64 * (ab2 % 3);
#pragma unroll
            for (int pf = 0; pf < 4; ++pf) {
                out[rowoff + pf * 16 + lm] = acc[mf][pf][r] + bo;
            }
        }
    }
}

// ---------------------------------------------------------------------------
extern "C" void kernel_launch(void* const* d_in, const int* in_sizes, int n_in,
                              void* d_out, int out_size, void* d_ws, size_t ws_size,
                              hipStream_t stream) {
    (void)in_sizes; (void)n_in; (void)out_size; (void)ws_size;
    const float* x = (const float*)d_in[0];
    const float* W = (const float*)d_in[1];
    const float* bias = (const float*)d_in[2];
    const float* u0 = (const float*)d_in[3];
    // d_in[4] (v0) unused: reference overwrites v before first use.
    float* out = (float*)d_out;

    float* Fm = (float*)d_ws;                                    // 5*64*64*4 = 80 KiB
    unsigned short* Wt = (unsigned short*)((char*)d_ws + 81920); // 576*576*2 = 648 KiB

    fm_kernel<<<5, 512, 0, stream>>>(W, u0, Fm);
    wbuild_kernel<<<16, 256, 0, stream>>>(Fm, Wt);
    dim3 g(1024, 3, 1);
    gemm_kernel<<<g, 256, 0, stream>>>(x, Wt, bias, out);
}

// Round 2
// 246.955 us; speedup vs baseline: 1.0256x; 1.0256x over previous
//
#include <hip/hip_runtime.h>

typedef __attribute__((ext_vector_type(8))) short short8;
typedef __attribute__((ext_vector_type(4))) float f32x4;
typedef __attribute__((ext_vector_type(4))) float float4v;

union BF8 { short8 v; unsigned long long q[2]; };

__device__ __forceinline__ unsigned short f2bf(float f) {
    unsigned int u = __float_as_uint(f);
    u += 0x7fffu + ((u >> 16) & 1u);
    return (unsigned short)(u >> 16);
}

#define FM_BYTES      81920
#define WTF_OFF       81920
#define WTOLD_OFF     745472
#define XT_OFF        1441792
#define WS_NEEDED     76939264UL

// ---------------------------------------------------------------------------
// Fused kernel: blocks 0..4 -> fm (power iteration + Taylor expm, unchanged
// logic from round 1); blocks 5.. -> x fp32 -> bf16 transpose into
// xT[n][h][half][w][c32] (channel-contiguous for MFMA K-dim).
// ---------------------------------------------------------------------------
__global__ __launch_bounds__(512) void fmconv_kernel(const float* __restrict__ W,
                                                     const float* __restrict__ u0,
                                                     const float* __restrict__ x,
                                                     float* __restrict__ FmOut,
                                                     unsigned short* __restrict__ xT) {
    __shared__ __align__(16) char smem[50448];
    const int t = threadIdx.x;

    if (blockIdx.x >= 5) {
        // ---- convert path: tile = 32 ch x 64 w for one (n,h,half,wb) ----
        unsigned short (*L)[36] = (unsigned short (*)[36])smem;
        const int tid = blockIdx.x - 5;
        const int wb = tid % 3;
        const int hh = tid / 3;          // half + 2*h + 384*n
        const int half = hh & 1;
        const int h = (hh >> 1) % 192;
        const int n = hh / 384;

        const int c = t >> 4;            // 0..31
        const int w4 = (t & 15) * 4;     // 0..60
        const float4v ld = *(const float4v*)(
            x + ((size_t)((n * 64 + half * 32 + c) * 192 + h)) * 192 + wb * 64 + w4);
#pragma unroll
        for (int k = 0; k < 4; ++k) {
            const int w = w4 + k;
            const int sb = ((c >> 2) ^ (w & 7)) & 7;
            L[w][sb * 4 + (c & 3)] = f2bf(ld[k]);
        }
        __syncthreads();

        const int w2 = t >> 3;           // 0..63
        const int cb = t & 7;            // logical channel block of 4
        const int sb2 = cb ^ (w2 & 7);
        const unsigned long long v = *(const unsigned long long*)(&L[w2][sb2 * 4]);
        const size_t tilebase =
            ((size_t)(((n * 192 + h) * 2 + half) * 192 + wb * 64)) * 32;
        *(unsigned long long*)(xT + tilebase + w2 * 32 + cb * 4) = v;
        return;
    }

    // ---- fm path ----
    float (*A)[65]   = (float (*)[65])smem;
    float (*Bu1)[65] = (float (*)[65])(smem + 16640);
    float (*Bu2)[65] = (float (*)[65])(smem + 33280);
    float* uS = (float*)(smem + 49920);
    float* vS = (float*)(smem + 50176);
    float* sigP = (float*)(smem + 50432);

    const int n = blockIdx.x;  // 0..4
    {
        const int i = t >> 3;
        const int j0 = (t & 7) * 8;
#pragma unroll
        for (int k = 0; k < 8; ++k) {
            const int j = j0 + k;
            const float wij = W[(i * 64 + j) * 5 + n];
            const float wji = W[(j * 64 + i) * 5 + n];
            A[i][j] = 0.5f * (wij - wji);
        }
    }
    __syncthreads();

    if (t < 64) {
        const int lane = t;
        float u = u0[n * 64 + lane];
        float s0 = u * u;
#pragma unroll
        for (int m = 1; m < 64; m <<= 1) s0 += __shfl_xor(s0, m);
        u = u / (sqrtf(s0) + 1e-12f);
        uS[lane] = u;
        for (int it = 0; it < 50; ++it) {
            float acc = 0.0f;
            for (int j = 0; j < 64; ++j) acc += A[lane][j] * uS[j];
            float ss = acc * acc;
#pragma unroll
            for (int m = 1; m < 64; m <<= 1) ss += __shfl_xor(ss, m);
            vS[lane] = acc / (sqrtf(ss) + 1e-12f);
            float acc2 = 0.0f;
            for (int i = 0; i < 64; ++i) acc2 += A[i][lane] * vS[i];
            float s2 = acc2 * acc2;
#pragma unroll
            for (int m = 1; m < 64; m <<= 1) s2 += __shfl_xor(s2, m);
            uS[lane] = acc2 / (sqrtf(s2) + 1e-12f);
        }
        float wsum = 0.0f;
        for (int j = 0; j < 64; ++j) wsum += A[lane][j] * uS[j];
        float part = vS[lane] * wsum;
#pragma unroll
        for (int m = 1; m < 64; m <<= 1) part += __shfl_xor(part, m);
        if (lane == 0) *sigP = part;
    }
    __syncthreads();

    const float sig = *sigP;
    {
        const int i = t >> 3;
        const int j0 = (t & 7) * 8;
#pragma unroll
        for (int k = 0; k < 8; ++k) A[i][j0 + k] = A[i][j0 + k] / sig;
    }
    __syncthreads();

    const int r = t >> 3;
    const int c0 = (t & 7) * 8;
    float fm[8];
#pragma unroll
    for (int k = 0; k < 8; ++k) {
        const float an = A[r][c0 + k];
        fm[k] = an;
        Bu1[r][c0 + k] = an;
    }
    __syncthreads();

    float* curp = &Bu1[0][0];
    float* nxtp = &Bu2[0][0];
    for (int term = 2; term <= 10; ++term) {
        float nx[8];
#pragma unroll
        for (int k = 0; k < 8; ++k) nx[k] = 0.0f;
        for (int j = 0; j < 64; ++j) {
            const float crj = curp[r * 65 + j];
            const float* arow = &A[j][c0];
#pragma unroll
            for (int k = 0; k < 8; ++k) nx[k] += crj * arow[k];
        }
        const float ft = (float)term;
#pragma unroll
        for (int k = 0; k < 8; ++k) {
            nx[k] = nx[k] / ft;
            nxtp[r * 65 + c0 + k] = nx[k];
            fm[k] += nx[k];
        }
        __syncthreads();
        float* tmp = curp; curp = nxtp; nxtp = tmp;
    }
#pragma unroll
    for (int k = 0; k < 8; ++k)
        FmOut[n * 4096 + r * 64 + c0 + k] = fm[k] + ((r == (c0 + k)) ? 1.0f : 0.0f);
}

// ---------------------------------------------------------------------------
// wbuild: Fm -> 3x3 real-ifft kernel -> folded weight, written BOTH as
//   Wtf (MFMA A-fragment order: [MF][cc][lane][8]) and Wt_old ([m][kap]).
// ---------------------------------------------------------------------------
__global__ __launch_bounds__(256) void wbuild_kernel(const float* __restrict__ Fm,
                                                     unsigned short* __restrict__ Wtf,
                                                     unsigned short* __restrict__ WtOld) {
    const int tg = blockIdx.x * 256 + threadIdx.x;  // 0..4095
    const int o = tg >> 6;
    const int i = tg & 63;
    float f[5];
#pragma unroll
    for (int nn = 0; nn < 5; ++nn) f[nn] = Fm[nn * 4096 + o * 64 + i];
    const int idx[3][3] = {{0, 1, 1}, {2, 3, 4}, {2, 4, 3}};
    float Kk[3][3];
#pragma unroll
    for (int u = 0; u < 3; ++u) {
#pragma unroll
        for (int v = 0; v < 3; ++v) {
            float s = 0.0f;
#pragma unroll
            for (int p = 0; p < 3; ++p) {
#pragma unroll
                for (int q = 0; q < 3; ++q) {
                    const int m = (p * u + q * v) % 3;
                    s += f[idx[p][q]] * ((m == 0) ? 1.0f : -0.5f);
                }
            }
            Kk[u][v] = s * (1.0f / 9.0f);
        }
    }
#pragma unroll
    for (int a = 0; a < 3; ++a) {
#pragma unroll
        for (int b = 0; b < 3; ++b) {
            const int m = (a * 3 + b) * 64 + o;
#pragma unroll
            for (int al = 0; al < 3; ++al) {
#pragma unroll
                for (int be = 0; be < 3; ++be) {
                    const int kh = (al - a + 4) % 3;
                    const int kw = (be - b + 4) % 3;
                    const unsigned short bf = f2bf(Kk[kh][kw]);
                    const int kap = (al * 3 + be) * 64 + i;
                    WtOld[m * 576 + kap] = bf;
                    const int MF = m >> 4, lm = m & 15;
                    const int cc = kap >> 5, lg = (kap >> 3) & 3, j = kap & 7;
                    Wtf[MF * 9216 + cc * 512 + (lg * 16 + lm) * 8 + j] = bf;
                }
            }
        }
    }
}

// ---------------------------------------------------------------------------
// gemm2: no LDS, no barriers. Z[m][p] = sum_kap Wt[m][kap] * X[kap][p].
// Block = 64 positions (one n,h0) x 192 m (blockIdx.y of 3). 4 waves x 48 m.
// K-loop: 18 steps of 32, 2-deep manual double buffer, direct global frag
// loads (A from Wtf frag-order, B from xT channel-contiguous).
// ---------------------------------------------------------------------------
__global__ __launch_bounds__(256, 3) void gemm2_kernel(
    const unsigned short* __restrict__ xT, const unsigned short* __restrict__ Wtf,
    const float* __restrict__ bias, float* __restrict__ out) {
    const int t = threadIdx.x;
    const int lane = t & 63;
    const int wv = t >> 6;
    const int bx = blockIdx.x;
    const int mg = blockIdx.y;
    const int n = bx >> 6;
    const int h0 = bx & 63;
    const int lm = lane & 15;
    const int lg = lane >> 4;

    f32x4 acc[3][4] = {};

    const unsigned short* xb = xT + (size_t)(n * 192 + h0) * 12288 + lm * 32 + lg * 8;
    const unsigned short* Wf = Wtf + (size_t)(mg * 12 + wv * 3) * 9216 + lane * 8;

#define LOADC(CC, AF, BF)                                                        \
    {                                                                            \
        const int ab_ = (CC) >> 1;                                               \
        const int al_ = ab_ / 3;                                                 \
        const int be_ = ab_ - al_ * 3;                                           \
        const int off_ = al_ * 786432 + ((CC) & 1) * 6144 + be_ * 2048;          \
        _Pragma("unroll") for (int pf = 0; pf < 4; ++pf)                         \
            BF[pf] = *(const short8*)(xb + off_ + pf * 512);                     \
        _Pragma("unroll") for (int mf = 0; mf < 3; ++mf)                         \
            AF[mf] = *(const short8*)(Wf + mf * 9216 + (CC) * 512);              \
    }

#define DOMFMA(AF, BF)                                                           \
    {                                                                            \
        _Pragma("unroll") for (int mf = 0; mf < 3; ++mf)                         \
            _Pragma("unroll") for (int pf = 0; pf < 4; ++pf)                     \
                acc[mf][pf] = __builtin_amdgcn_mfma_f32_16x16x32_bf16(           \
                    AF[mf], BF[pf], acc[mf][pf], 0, 0, 0);                       \
    }

    short8 afA[3], bfA[4], afB[3], bfB[4];
    LOADC(0, afA, bfA);
    for (int cc = 0; cc < 18; cc += 2) {
        LOADC(cc + 1, afB, bfB);
        DOMFMA(afA, bfA);
        const int cn = (cc + 2 < 18) ? (cc + 2) : 0;  // harmless redundant tail
        LOADC(cn, afA, bfA);
        DOMFMA(afB, bfB);
    }
#undef LOADC
#undef DOMFMA

#pragma unroll
    for (int mf = 0; mf < 3; ++mf) {
#pragma unroll
        for (int r = 0; r < 4; ++r) {
            const int m = mg * 192 + wv * 48 + mf * 16 + lg * 4 + r;
            const int o = m & 63;
            const int ab2 = m >> 6;
            const float bo = bias[o];
            const int rowoff =
                ((n * 64 + o) * 192 + (h0 + 64 * (ab2 / 3))) * 192 + 64 * (ab2 % 3);
#pragma unroll
            for (int pf = 0; pf < 4; ++pf) {
                out[rowoff + pf * 16 + lm] = acc[mf][pf][r] + bo;
            }
        }
    }
}

// ---------------------------------------------------------------------------
// Fallback GEMM (round-1, LDS-staged fp32 path) if ws is too small for xT.
// ---------------------------------------------------------------------------
__global__ __launch_bounds__(256) void gemm_fallback(const float* __restrict__ x,
                                                     const unsigned short* __restrict__ Wt,
                                                     const float* __restrict__ bias,
                                                     float* __restrict__ out) {
    __shared__ unsigned short Xs[64][36];
    const int t = threadIdx.x;
    const int lane = t & 63;
    const int wv = t >> 6;
    const int pblk = blockIdx.x;
    const int mg = blockIdx.y;
    const int n = pblk >> 6;
    const int h0 = pblk & 63;
    const int wave_m0 = mg * 192 + wv * 48;
    const int lm = lane & 15;
    const int lg = lane >> 4;

    f32x4 acc[3][4] = {};
    const float* xb = x + n * 64 * 36864;
    const int w0s = t & 63;
    const int kq = (t >> 6) * 8;

    for (int c = 0; c < 18; ++c) {
        const int ab = c >> 1;
        const int al = ab / 3;
        const int be = ab % 3;
        const int ih = (c & 1) * 32;
        const int base = ih * 36864 + (h0 + 64 * al) * 192 + 64 * be + w0s;
#pragma unroll
        for (int s = 0; s < 8; ++s) {
            const int kp = kq + s;
            Xs[w0s][kp] = f2bf(xb[base + kp * 36864]);
        }
        __syncthreads();
        const int kb = c * 32 + lg * 8;
        short8 af[3];
#pragma unroll
        for (int mf = 0; mf < 3; ++mf)
            af[mf] = *(const short8*)(Wt + (wave_m0 + mf * 16 + lm) * 576 + kb);
        short8 bf[4];
#pragma unroll
        for (int pf = 0; pf < 4; ++pf) {
            const unsigned long long* s8 =
                (const unsigned long long*)(&Xs[pf * 16 + lm][lg * 8]);
            BF8 u;
            u.q[0] = s8[0];
            u.q[1] = s8[1];
            bf[pf] = u.v;
        }
#pragma unroll
        for (int mf = 0; mf < 3; ++mf)
#pragma unroll
            for (int pf = 0; pf < 4; ++pf)
                acc[mf][pf] = __builtin_amdgcn_mfma_f32_16x16x32_bf16(
                    af[mf], bf[pf], acc[mf][pf], 0, 0, 0);
        __syncthreads();
    }

#pragma unroll
    for (int mf = 0; mf < 3; ++mf)
#pragma unroll
        for (int r = 0; r < 4; ++r) {
            const int m = wave_m0 + mf * 16 + lg * 4 + r;
            const int o = m & 63;
            const int ab2 = m >> 6;
            const float bo = bias[o];
            const int rowoff =
                ((n * 64 + o) * 192 + (h0 + 64 * (ab2 / 3))) * 192 + 64 * (ab2 % 3);
#pragma unroll
            for (int pf = 0; pf < 4; ++pf)
                out[rowoff + pf * 16 + lm] = acc[mf][pf][r] + bo;
        }
}

// ---------------------------------------------------------------------------
extern "C" void kernel_launch(void* const* d_in, const int* in_sizes, int n_in,
                              void* d_out, int out_size, void* d_ws, size_t ws_size,
                              hipStream_t stream) {
    (void)in_sizes; (void)n_in; (void)out_size;
    const float* x = (const float*)d_in[0];
    const float* W = (const float*)d_in[1];
    const float* bias = (const float*)d_in[2];
    const float* u0 = (const float*)d_in[3];
    float* out = (float*)d_out;

    float* Fm = (float*)d_ws;
    unsigned short* Wtf = (unsigned short*)((char*)d_ws + WTF_OFF);
    unsigned short* WtOld = (unsigned short*)((char*)d_ws + WTOLD_OFF);
    unsigned short* xT = (unsigned short*)((char*)d_ws + XT_OFF);

    const bool big_ws = (ws_size >= WS_NEEDED);

    if (big_ws) {
        fmconv_kernel<<<5 + 18432, 512, 0, stream>>>(W, u0, x, Fm, xT);
        wbuild_kernel<<<16, 256, 0, stream>>>(Fm, Wtf, WtOld);
        dim3 g(1024, 3, 1);
        gemm2_kernel<<<g, 256, 0, stream>>>(xT, Wtf, bias, out);
    } else {
        fmconv_kernel<<<5, 512, 0, stream>>>(W, u0, x, Fm, xT);
        wbuild_kernel<<<16, 256, 0, stream>>>(Fm, Wtf, WtOld);
        dim3 g(1024, 3, 1);
        gemm_fallback<<<g, 256, 0, stream>>>(x, WtOld, bias, out);
    }
}

// Round 3
// 211.300 us; speedup vs baseline: 1.1986x; 1.1687x over previous
//
#include <hip/hip_runtime.h>

typedef __attribute__((ext_vector_type(8))) short short8;
typedef __attribute__((ext_vector_type(4))) float f32x4;
typedef __attribute__((ext_vector_type(4))) float float4v;
typedef __attribute__((ext_vector_type(2))) float float2v;

__device__ __forceinline__ unsigned short f2bf(float f) {
    unsigned int u = __float_as_uint(f);
    u += 0x7fffu + ((u >> 16) & 1u);
    return (unsigned short)(u >> 16);
}

__device__ __forceinline__ float wavesum(float x) {
#pragma unroll
    for (int m = 1; m < 64; m <<= 1) x += __shfl_xor(x, m);
    return x;
}

// dot(row[0..63], y-distributed-one-per-lane) via readlane broadcasts.
__device__ __forceinline__ float matvec64(const float* row, float y) {
    float ac[8] = {0.f, 0.f, 0.f, 0.f, 0.f, 0.f, 0.f, 0.f};
#pragma unroll
    for (int j = 0; j < 64; ++j) {
        const float yj =
            __uint_as_float(__builtin_amdgcn_readlane(__float_as_uint(y), j));
        ac[j & 7] = fmaf(row[j], yj, ac[j & 7]);
    }
    return ((ac[0] + ac[1]) + (ac[2] + ac[3])) + ((ac[4] + ac[5]) + (ac[6] + ac[7]));
}

#define WTF_OFF       81920
#define WTOLD_OFF     745472
#define XT_OFF        1441792
#define WS_NEEDED     76939264UL

// ---------------------------------------------------------------------------
// Fused: blocks 0..4 = fm (register power iteration + LDS Taylor);
//        blocks 5..  = x fp32 -> bf16 transpose to xT[n][h][half][w][c32].
// Shared static LDS: 35840 B (4 blocks/CU for convert path).
// ---------------------------------------------------------------------------
__global__ __launch_bounds__(512) void fmconv_kernel(const float* __restrict__ W,
                                                     const float* __restrict__ u0,
                                                     const float* __restrict__ x,
                                                     float* __restrict__ FmOut,
                                                     unsigned short* __restrict__ xT) {
    __shared__ __align__(16) char smem[35840];
    const int t = threadIdx.x;

    if (blockIdx.x >= 5) {
        // ---- convert path: one (n,h,half,wb): 32 ch x 64 w tile ----
        float (*L)[66] = (float (*)[66])smem;
        const int tid = blockIdx.x - 5;
        const int wb = tid % 3;
        const int hh = tid / 3;
        const int half = hh & 1;
        const int h = (hh >> 1) % 192;
        const int n = hh / 384;

        // phase 1: coalesced float4 along w
        {
            const int c = t >> 4;             // 0..31
            const int w4 = (t & 15) * 4;      // 0..60
            const float4v ld = *(const float4v*)(
                x + ((size_t)((n * 64 + half * 32 + c) * 192 + h)) * 192 + wb * 64 + w4);
            float2v lo, hi;
            lo[0] = ld[0]; lo[1] = ld[1]; hi[0] = ld[2]; hi[1] = ld[3];
            *(float2v*)(&L[c][w4]) = lo;
            *(float2v*)(&L[c][w4 + 2]) = hi;
        }
        __syncthreads();

        // phase 2: read 4 channels at one w, pack bf16x4, coalesced 8B store
        {
            const int w2 = t >> 3;            // 0..63
            const int c4 = (t & 7) * 4;       // 0..28
            union { unsigned short u[4]; unsigned long long q; } pk;
#pragma unroll
            for (int k = 0; k < 4; ++k) pk.u[k] = f2bf(L[c4 + k][w2]);
            const size_t tilebase =
                ((size_t)(((n * 192 + h) * 2 + half))) * 6144 + wb * 64 * 32;
            *(unsigned long long*)(xT + tilebase + w2 * 32 + c4) = pk.q;
        }
        return;
    }

    // ---- fm path ----
    float (*A)[68]  = (float (*)[68])smem;                  // 17408 B
    float (*Bu)[68] = (float (*)[68])(smem + 17408);        // 17408 B
    float* sigP = (float*)(smem + 34816);

    const int n = blockIdx.x;  // 0..4
    {
        const int i = t >> 3;
        const int j0 = (t & 7) * 8;
#pragma unroll
        for (int k = 0; k < 8; ++k) {
            const int j = j0 + k;
            const float wij = W[(i * 64 + j) * 5 + n];
            const float wji = W[(j * 64 + i) * 5 + n];
            A[i][j] = 0.5f * (wij - wji);
        }
    }
    __syncthreads();

    // register-row power iteration on wave 0 (A^T = -A used for the u-update)
    if (t < 64) {
        float row[64];
#pragma unroll
        for (int q = 0; q < 16; ++q)
            *(float4v*)&row[q * 4] = *(const float4v*)(&A[t][q * 4]);
        float uv = u0[n * 64 + t];
        uv = uv / (sqrtf(wavesum(uv * uv)) + 1e-12f);
        float vv = 0.0f;
        for (int it = 0; it < 50; ++it) {
            const float w = matvec64(row, uv);           // (A u)_i
            vv = w / (sqrtf(wavesum(w * w)) + 1e-12f);   // v = l2n(A u)
            const float z = matvec64(row, vv);           // (A v)_j
            uv = -z / (sqrtf(wavesum(z * z)) + 1e-12f);  // u = l2n(A^T v) = -l2n(A v)
        }
        const float w2 = matvec64(row, uv);
        const float sig = wavesum(vv * w2);              // sum_i v_i (A u)_i
        if (t == 0) *sigP = sig;
    }
    __syncthreads();

    const float sig = *sigP;
    {
        const int i = t >> 3;
        const int j0 = (t & 7) * 8;
#pragma unroll
        for (int k = 0; k < 8; ++k) A[i][j0 + k] = A[i][j0 + k] / sig;  // An
    }
    __syncthreads();

    // Taylor: curr(term1) = An lives in A; single ping buffer Bu thereafter.
    const int r = t >> 3;
    const int c0 = (t & 7) * 8;
    float fm[8];
#pragma unroll
    for (int k = 0; k < 8; ++k) fm[k] = A[r][c0 + k];

    const float* curbase = &A[0][0];
    for (int term = 2; term <= 10; ++term) {
        float nx[8];
#pragma unroll
        for (int k = 0; k < 8; ++k) nx[k] = 0.0f;
        for (int j = 0; j < 64; ++j) {
            const float crj = curbase[r * 68 + j];
            const float* arow = &A[j][c0];
#pragma unroll
            for (int k = 0; k < 8; ++k) nx[k] += crj * arow[k];
        }
        const float ft = (float)term;
#pragma unroll
        for (int k = 0; k < 8; ++k) {
            nx[k] = nx[k] / ft;
            fm[k] += nx[k];
        }
        __syncthreads();  // all reads of Bu/A-as-curr done
#pragma unroll
        for (int k = 0; k < 8; ++k) Bu[r][c0 + k] = nx[k];
        __syncthreads();  // writes visible
        curbase = &Bu[0][0];
    }
#pragma unroll
    for (int k = 0; k < 8; ++k)
        FmOut[n * 4096 + r * 64 + c0 + k] = fm[k] + ((r == (c0 + k)) ? 1.0f : 0.0f);
}

// ---------------------------------------------------------------------------
// wbuild: Fm -> 3x3 real-ifft -> folded weight; Wtf (16x16 A-frag order) and
// WtOld ([m][kap]) for the fallback path. (Unchanged from round 2.)
// ---------------------------------------------------------------------------
__global__ __launch_bounds__(256) void wbuild_kernel(const float* __restrict__ Fm,
                                                     unsigned short* __restrict__ Wtf,
                                                     unsigned short* __restrict__ WtOld) {
    const int tg = blockIdx.x * 256 + threadIdx.x;  // 0..4095
    const int o = tg >> 6;
    const int i = tg & 63;
    float f[5];
#pragma unroll
    for (int nn = 0; nn < 5; ++nn) f[nn] = Fm[nn * 4096 + o * 64 + i];
    const int idx[3][3] = {{0, 1, 1}, {2, 3, 4}, {2, 4, 3}};
    float Kk[3][3];
#pragma unroll
    for (int u = 0; u < 3; ++u) {
#pragma unroll
        for (int v = 0; v < 3; ++v) {
            float s = 0.0f;
#pragma unroll
            for (int p = 0; p < 3; ++p) {
#pragma unroll
                for (int q = 0; q < 3; ++q) {
                    const int m = (p * u + q * v) % 3;
                    s += f[idx[p][q]] * ((m == 0) ? 1.0f : -0.5f);
                }
            }
            Kk[u][v] = s * (1.0f / 9.0f);
        }
    }
#pragma unroll
    for (int a = 0; a < 3; ++a) {
#pragma unroll
        for (int b = 0; b < 3; ++b) {
            const int m = (a * 3 + b) * 64 + o;
#pragma unroll
            for (int al = 0; al < 3; ++al) {
#pragma unroll
                for (int be = 0; be < 3; ++be) {
                    const int kh = (al - a + 4) % 3;
                    const int kw = (be - b + 4) % 3;
                    const unsigned short bf = f2bf(Kk[kh][kw]);
                    const int kap = (al * 3 + be) * 64 + i;
                    WtOld[m * 576 + kap] = bf;
                    const int MF = m >> 4, lm = m & 15;
                    const int cc = kap >> 5, lg = (kap >> 3) & 3, j = kap & 7;
                    Wtf[MF * 9216 + cc * 512 + (lg * 16 + lm) * 8 + j] = bf;
                }
            }
        }
    }
}

// ---------------------------------------------------------------------------
// gemm3: no LDS/barriers; wave = 96m x 64p (6 A-frags x 4 B-frags, 24 MFMA
// per 10 dwordx4 loads). Block = 192m x 2 h0-panels (4 waves, 2m x 2p).
// A shared across wp-pair, B shared across wm-pair (L1 dedup).
// ---------------------------------------------------------------------------
__global__ __launch_bounds__(256, 2) void gemm3_kernel(
    const unsigned short* __restrict__ xT, const unsigned short* __restrict__ Wtf,
    const float* __restrict__ bias, float* __restrict__ out) {
    const int t = threadIdx.x;
    const int lane = t & 63;
    const int wv = t >> 6;
    const int wm = wv >> 1;      // 0..1: m-half of the block
    const int wp = wv & 1;       // 0..1: which h0 panel
    const int bx = blockIdx.x;
    const int mg = blockIdx.y;
    const int n = bx >> 5;
    const int h0 = (bx & 31) * 2 + wp;
    const int lm = lane & 15;
    const int lg = lane >> 4;

    f32x4 acc[6][4] = {};

    const unsigned short* xb = xT + (size_t)(n * 192 + h0) * 12288 + lm * 32 + lg * 8;
    const unsigned short* Wf = Wtf + (size_t)(mg * 12 + wm * 6) * 9216 + lane * 8;

#define LOADC(CC, AF, BF)                                                        \
    {                                                                            \
        const int ab_ = (CC) >> 1;                                               \
        const int al_ = ab_ / 3;                                                 \
        const int be_ = ab_ - al_ * 3;                                           \
        const int off_ = al_ * 786432 + ((CC) & 1) * 6144 + be_ * 2048;          \
        _Pragma("unroll") for (int pf = 0; pf < 4; ++pf)                         \
            BF[pf] = *(const short8*)(xb + off_ + pf * 512);                     \
        _Pragma("unroll") for (int mf = 0; mf < 6; ++mf)                         \
            AF[mf] = *(const short8*)(Wf + mf * 9216 + (CC) * 512);              \
    }

#define DOMFMA(AF, BF)                                                           \
    {                                                                            \
        _Pragma("unroll") for (int mf = 0; mf < 6; ++mf)                         \
            _Pragma("unroll") for (int pf = 0; pf < 4; ++pf)                     \
                acc[mf][pf] = __builtin_amdgcn_mfma_f32_16x16x32_bf16(           \
                    AF[mf], BF[pf], acc[mf][pf], 0, 0, 0);                       \
    }

    short8 afA[6], bfA[4], afB[6], bfB[4];
    LOADC(0, afA, bfA);
    for (int cc = 0; cc < 18; cc += 2) {
        LOADC(cc + 1, afB, bfB);
        DOMFMA(afA, bfA);
        const int cn = (cc + 2 < 18) ? (cc + 2) : 0;  // harmless redundant tail
        LOADC(cn, afA, bfA);
        DOMFMA(afB, bfB);
    }
#undef LOADC
#undef DOMFMA

#pragma unroll
    for (int mf = 0; mf < 6; ++mf) {
#pragma unroll
        for (int r = 0; r < 4; ++r) {
            const int m = mg * 192 + wm * 96 + mf * 16 + lg * 4 + r;
            const int o = m & 63;
            const int ab2 = m >> 6;
            const float bo = bias[o];
            const int rowoff =
                ((n * 64 + o) * 192 + (h0 + 64 * (ab2 / 3))) * 192 + 64 * (ab2 % 3);
#pragma unroll
            for (int pf = 0; pf < 4; ++pf) {
                out[rowoff + pf * 16 + lm] = acc[mf][pf][r] + bo;
            }
        }
    }
}

// ---------------------------------------------------------------------------
// Fallback GEMM (round-1 validated, LDS-staged fp32) if ws too small for xT.
// ---------------------------------------------------------------------------
__global__ __launch_bounds__(256) void gemm_fallback(const float* __restrict__ x,
                                                     const unsigned short* __restrict__ Wt,
                                                     const float* __restrict__ bias,
                                                     float* __restrict__ out) {
    __shared__ unsigned short Xs[64][36];
    const int t = threadIdx.x;
    const int lane = t & 63;
    const int wv = t >> 6;
    const int pblk = blockIdx.x;
    const int mg = blockIdx.y;
    const int n = pblk >> 6;
    const int h0 = pblk & 63;
    const int wave_m0 = mg * 192 + wv * 48;
    const int lm = lane & 15;
    const int lg = lane >> 4;

    f32x4 acc[3][4] = {};
    const float* xb = x + n * 64 * 36864;
    const int w0s = t & 63;
    const int kq = (t >> 6) * 8;

    for (int c = 0; c < 18; ++c) {
        const int ab = c >> 1;
        const int al = ab / 3;
        const int be = ab % 3;
        const int ih = (c & 1) * 32;
        const int base = ih * 36864 + (h0 + 64 * al) * 192 + 64 * be + w0s;
#pragma unroll
        for (int s = 0; s < 8; ++s) {
            const int kp = kq + s;
            Xs[w0s][kp] = f2bf(xb[base + kp * 36864]);
        }
        __syncthreads();
        const int kb = c * 32 + lg * 8;
        short8 af[3];
#pragma unroll
        for (int mf = 0; mf < 3; ++mf)
            af[mf] = *(const short8*)(Wt + (wave_m0 + mf * 16 + lm) * 576 + kb);
        short8 bf[4];
#pragma unroll
        for (int pf = 0; pf < 4; ++pf) {
            union { short8 v; unsigned long long q[2]; } u;
            const unsigned long long* s8 =
                (const unsigned long long*)(&Xs[pf * 16 + lm][lg * 8]);
            u.q[0] = s8[0];
            u.q[1] = s8[1];
            bf[pf] = u.v;
        }
#pragma unroll
        for (int mf = 0; mf < 3; ++mf)
#pragma unroll
            for (int pf = 0; pf < 4; ++pf)
                acc[mf][pf] = __builtin_amdgcn_mfma_f32_16x16x32_bf16(
                    af[mf], bf[pf], acc[mf][pf], 0, 0, 0);
        __syncthreads();
    }

#pragma unroll
    for (int mf = 0; mf < 3; ++mf)
#pragma unroll
        for (int r = 0; r < 4; ++r) {
            const int m = wave_m0 + mf * 16 + lg * 4 + r;
            const int o = m & 63;
            const int ab2 = m >> 6;
            const float bo = bias[o];
            const int rowoff =
                ((n * 64 + o) * 192 + (h0 + 64 * (ab2 / 3))) * 192 + 64 * (ab2 % 3);
#pragma unroll
            for (int pf = 0; pf < 4; ++pf)
                out[rowoff + pf * 16 + lm] = acc[mf][pf][r] + bo;
        }
}

// ---------------------------------------------------------------------------
extern "C" void kernel_launch(void* const* d_in, const int* in_sizes, int n_in,
                              void* d_out, int out_size, void* d_ws, size_t ws_size,
                              hipStream_t stream) {
    (void)in_sizes; (void)n_in; (void)out_size;
    const float* x = (const float*)d_in[0];
    const float* W = (const float*)d_in[1];
    const float* bias = (const float*)d_in[2];
    const float* u0 = (const float*)d_in[3];
    float* out = (float*)d_out;

    float* Fm = (float*)d_ws;
    unsigned short* Wtf = (unsigned short*)((char*)d_ws + WTF_OFF);
    unsigned short* WtOld = (unsigned short*)((char*)d_ws + WTOLD_OFF);
    unsigned short* xT = (unsigned short*)((char*)d_ws + XT_OFF);

    const bool big_ws = (ws_size >= WS_NEEDED);

    if (big_ws) {
        fmconv_kernel<<<5 + 18432, 512, 0, stream>>>(W, u0, x, Fm, xT);
        wbuild_kernel<<<16, 256, 0, stream>>>(Fm, Wtf, WtOld);
        dim3 g(512, 3, 1);
        gemm3_kernel<<<g, 256, 0, stream>>>(xT, Wtf, bias, out);
    } else {
        fmconv_kernel<<<5, 512, 0, stream>>>(W, u0, x, Fm, xT);
        wbuild_kernel<<<16, 256, 0, stream>>>(Fm, Wtf, WtOld);
        dim3 g(1024, 3, 1);
        gemm_fallback<<<g, 256, 0, stream>>>(x, WtOld, bias, out);
    }
}

// Round 4
// 157.556 us; speedup vs baseline: 1.6075x; 1.3411x over previous
//
#include <hip/hip_runtime.h>

typedef __attribute__((ext_vector_type(8))) short short8;
typedef __attribute__((ext_vector_type(4))) float f32x4;
typedef __attribute__((ext_vector_type(4))) float float4v;
typedef __attribute__((ext_vector_type(2))) float float2v;

__device__ __forceinline__ unsigned short f2bf(float f) {
    unsigned int u = __float_as_uint(f);
    u += 0x7fffu + ((u >> 16) & 1u);
    return (unsigned short)(u >> 16);
}

__device__ __forceinline__ float wavesum(float x) {
#pragma unroll
    for (int m = 1; m < 64; m <<= 1) x += __shfl_xor(x, m);
    return x;
}

// dot(row[0..63], y-distributed-one-per-lane) via readlane broadcasts.
__device__ __forceinline__ float matvec64(const float* row, float y) {
    float ac[8] = {0.f, 0.f, 0.f, 0.f, 0.f, 0.f, 0.f, 0.f};
#pragma unroll
    for (int j = 0; j < 64; ++j) {
        const float yj =
            __uint_as_float(__builtin_amdgcn_readlane(__float_as_uint(y), j));
        ac[j & 7] = fmaf(row[j], yj, ac[j & 7]);
    }
    return ((ac[0] + ac[1]) + (ac[2] + ac[3])) + ((ac[4] + ac[5]) + (ac[6] + ac[7]));
}

// async 16B global -> LDS (linear dest: wave-uniform base + lane*16)
__device__ __forceinline__ void gload16(const void* g, void* l) {
    __builtin_amdgcn_global_load_lds(
        (const __attribute__((address_space(1))) unsigned int*)g,
        (__attribute__((address_space(3))) unsigned int*)l, 16, 0, 0);
}

#define WTF_OFF       81920
#define WTOLD_OFF     745472
#define XT_OFF        1441792
#define WS_NEEDED     76939264UL

// ---------------------------------------------------------------------------
// Fused: blocks 0..4 = fm (register power iteration + LDS Taylor);
//        blocks 5..  = x fp32 -> bf16 transpose to xT[n][h][half][w][c32].
// ---------------------------------------------------------------------------
__global__ __launch_bounds__(512) void fmconv_kernel(const float* __restrict__ W,
                                                     const float* __restrict__ u0,
                                                     const float* __restrict__ x,
                                                     float* __restrict__ FmOut,
                                                     unsigned short* __restrict__ xT) {
    __shared__ __align__(16) char smem[35840];
    const int t = threadIdx.x;

    if (blockIdx.x >= 5) {
        // ---- convert path: one (n,h,half,wb): 32 ch x 64 w tile ----
        float (*L)[66] = (float (*)[66])smem;
        const int tid = blockIdx.x - 5;
        const int wb = tid % 3;
        const int hh = tid / 3;
        const int half = hh & 1;
        const int h = (hh >> 1) % 192;
        const int n = hh / 384;

        {
            const int c = t >> 4;             // 0..31
            const int w4 = (t & 15) * 4;      // 0..60
            const float4v ld = *(const float4v*)(
                x + ((size_t)((n * 64 + half * 32 + c) * 192 + h)) * 192 + wb * 64 + w4);
            float2v lo, hi;
            lo[0] = ld[0]; lo[1] = ld[1]; hi[0] = ld[2]; hi[1] = ld[3];
            *(float2v*)(&L[c][w4]) = lo;
            *(float2v*)(&L[c][w4 + 2]) = hi;
        }
        __syncthreads();

        {
            const int w2 = t >> 3;            // 0..63
            const int c4 = (t & 7) * 4;       // 0..28
            union { unsigned short u[4]; unsigned long long q; } pk;
#pragma unroll
            for (int k = 0; k < 4; ++k) pk.u[k] = f2bf(L[c4 + k][w2]);
            const size_t tilebase =
                ((size_t)(((n * 192 + h) * 2 + half))) * 6144 + wb * 64 * 32;
            *(unsigned long long*)(xT + tilebase + w2 * 32 + c4) = pk.q;
        }
        return;
    }

    // ---- fm path ----
    float (*A)[68]  = (float (*)[68])smem;
    float (*Bu)[68] = (float (*)[68])(smem + 17408);
    float* sigP = (float*)(smem + 34816);

    const int n = blockIdx.x;  // 0..4
    {
        const int i = t >> 3;
        const int j0 = (t & 7) * 8;
#pragma unroll
        for (int k = 0; k < 8; ++k) {
            const int j = j0 + k;
            const float wij = W[(i * 64 + j) * 5 + n];
            const float wji = W[(j * 64 + i) * 5 + n];
            A[i][j] = 0.5f * (wij - wji);
        }
    }
    __syncthreads();

    if (t < 64) {
        float row[64];
#pragma unroll
        for (int q = 0; q < 16; ++q)
            *(float4v*)&row[q * 4] = *(const float4v*)(&A[t][q * 4]);
        float uv = u0[n * 64 + t];
        uv = uv / (sqrtf(wavesum(uv * uv)) + 1e-12f);
        float vv = 0.0f;
        for (int it = 0; it < 50; ++it) {
            const float w = matvec64(row, uv);
            vv = w / (sqrtf(wavesum(w * w)) + 1e-12f);
            const float z = matvec64(row, vv);
            uv = -z / (sqrtf(wavesum(z * z)) + 1e-12f);
        }
        const float w2 = matvec64(row, uv);
        const float sig = wavesum(vv * w2);
        if (t == 0) *sigP = sig;
    }
    __syncthreads();

    const float sig = *sigP;
    {
        const int i = t >> 3;
        const int j0 = (t & 7) * 8;
#pragma unroll
        for (int k = 0; k < 8; ++k) A[i][j0 + k] = A[i][j0 + k] / sig;
    }
    __syncthreads();

    const int r = t >> 3;
    const int c0 = (t & 7) * 8;
    float fm[8];
#pragma unroll
    for (int k = 0; k < 8; ++k) fm[k] = A[r][c0 + k];

    const float* curbase = &A[0][0];
    for (int term = 2; term <= 10; ++term) {
        float nx[8];
#pragma unroll
        for (int k = 0; k < 8; ++k) nx[k] = 0.0f;
        for (int j = 0; j < 64; ++j) {
            const float crj = curbase[r * 68 + j];
            const float* arow = &A[j][c0];
#pragma unroll
            for (int k = 0; k < 8; ++k) nx[k] += crj * arow[k];
        }
        const float ft = (float)term;
#pragma unroll
        for (int k = 0; k < 8; ++k) {
            nx[k] = nx[k] / ft;
            fm[k] += nx[k];
        }
        __syncthreads();
#pragma unroll
        for (int k = 0; k < 8; ++k) Bu[r][c0 + k] = nx[k];
        __syncthreads();
        curbase = &Bu[0][0];
    }
#pragma unroll
    for (int k = 0; k < 8; ++k)
        FmOut[n * 4096 + r * 64 + c0 + k] = fm[k] + ((r == (c0 + k)) ? 1.0f : 0.0f);
}

// ---------------------------------------------------------------------------
// wbuild: Fm -> 3x3 real-ifft -> folded weight; Wtf (16x16 A-frag order) and
// WtOld ([m][kap]) for the fallback path.
// ---------------------------------------------------------------------------
__global__ __launch_bounds__(256) void wbuild_kernel(const float* __restrict__ Fm,
                                                     unsigned short* __restrict__ Wtf,
                                                     unsigned short* __restrict__ WtOld) {
    const int tg = blockIdx.x * 256 + threadIdx.x;  // 0..4095
    const int o = tg >> 6;
    const int i = tg & 63;
    float f[5];
#pragma unroll
    for (int nn = 0; nn < 5; ++nn) f[nn] = Fm[nn * 4096 + o * 64 + i];
    const int idx[3][3] = {{0, 1, 1}, {2, 3, 4}, {2, 4, 3}};
    float Kk[3][3];
#pragma unroll
    for (int u = 0; u < 3; ++u) {
#pragma unroll
        for (int v = 0; v < 3; ++v) {
            float s = 0.0f;
#pragma unroll
            for (int p = 0; p < 3; ++p) {
#pragma unroll
                for (int q = 0; q < 3; ++q) {
                    const int m = (p * u + q * v) % 3;
                    s += f[idx[p][q]] * ((m == 0) ? 1.0f : -0.5f);
                }
            }
            Kk[u][v] = s * (1.0f / 9.0f);
        }
    }
#pragma unroll
    for (int a = 0; a < 3; ++a) {
#pragma unroll
        for (int b = 0; b < 3; ++b) {
            const int m = (a * 3 + b) * 64 + o;
#pragma unroll
            for (int al = 0; al < 3; ++al) {
#pragma unroll
                for (int be = 0; be < 3; ++be) {
                    const int kh = (al - a + 4) % 3;
                    const int kw = (be - b + 4) % 3;
                    const unsigned short bf = f2bf(Kk[kh][kw]);
                    const int kap = (al * 3 + be) * 64 + i;
                    WtOld[m * 576 + kap] = bf;
                    const int MF = m >> 4, lm = m & 15;
                    const int cc = kap >> 5, lg = (kap >> 3) & 3, j = kap & 7;
                    Wtf[MF * 9216 + cc * 512 + (lg * 16 + lm) * 8 + j] = bf;
                }
            }
        }
    }
}

// ---------------------------------------------------------------------------
// gemm4: LDS double-buffered (m97-analog). Block = 192m x 128p, 4 waves
// (2wm x 2wp), wave = 96m x 64p. K-chunk = 64 kap (one (al,be), both halves).
// LDS/buffer: A 24KB (verbatim Wtf slice) + B 16KB ([cc][p][c32]) = 40KB;
// double-buffered = 80KB -> 2 blocks/CU. Staged via global_load_lds x16B.
// ---------------------------------------------------------------------------
__global__ __launch_bounds__(256, 2) void gemm4_kernel(
    const unsigned short* __restrict__ xT, const unsigned short* __restrict__ Wtf,
    const float* __restrict__ bias, float* __restrict__ out) {
    __shared__ __align__(16) char smem[81920];
    const int t = threadIdx.x;
    const int lane = t & 63;
    const int wv = t >> 6;          // 0..3
    const int wm = wv >> 1;         // m-half
    const int wp = wv & 1;          // p-half (= which h0 row)
    const int lm = lane & 15;
    const int lg = lane >> 4;

    // XCD-bijective swizzle (nwg=1536, 1536%8==0): XCD k gets work k*192..+191
    // = panels 64k..64k+63 with all 3 mg adjacent -> xT L2 sharing.
    const int orig = blockIdx.x;
    const int swz = (orig & 7) * 192 + (orig >> 3);
    const int mg = swz % 3;
    const int panel = swz / 3;      // 0..511
    const int n = panel >> 5;
    const int h0b = (panel & 31) * 2;

    f32x4 acc[6][4] = {};

    // stage one K-chunk (KC=al*3+be) into buffer BUF.
    // LDS linear: bytes [0,24576) = A region (12 mf-slabs x 2KB, verbatim
    // Wtf[mg*12+mfL][2KC..2KC+1][lane][8]); [24576,40960) = B region
    // [ccL(2)][p(128)][c(32)] (verbatim xT rows).
#define STAGE(BUF, KC)                                                          \
    {                                                                           \
        const int al_ = (KC) / 3, be_ = (KC) - 3 * ((KC) / 3);                  \
        _Pragma("unroll") for (int it = 0; it < 10; ++it) {                     \
            char* ldsb = smem + (BUF) * 40960 + it * 4096 + wv * 1024;          \
            const unsigned short* src;                                          \
            if (it < 6) {                                                       \
                const int e = it * 2048 + t * 8;  /* elem in A region */        \
                const int mfL = e >> 10;                                        \
                const int rem = e & 1023;                                       \
                src = Wtf + (mg * 12 + mfL) * 9216 + (KC) * 1024 + rem;         \
            } else {                                                            \
                const int e = (it - 6) * 2048 + t * 8;                          \
                const int ccL = e >> 12;                                        \
                const int rem = e & 4095;                                       \
                const int p_ = rem >> 5;                                        \
                const int c_ = rem & 31;                                        \
                const int h_ = h0b + (p_ >> 6) + 64 * al_;                      \
                const int w_ = be_ * 64 + (p_ & 63);                            \
                src = xT + ((size_t)((n * 192 + h_) * 2 + ccL)) * 6144 +        \
                      w_ * 32 + c_;                                             \
            }                                                                   \
            gload16(src, ldsb);                                                 \
        }                                                                       \
    }

#define COMPUTE(BUF)                                                            \
    {                                                                           \
        const char* base = smem + (BUF) * 40960;                                \
        short8 af[12];                                                          \
        short8 bf[8];                                                           \
        _Pragma("unroll") for (int mf = 0; mf < 6; ++mf)                        \
            _Pragma("unroll") for (int cl = 0; cl < 2; ++cl)                    \
                af[mf * 2 + cl] = *(const short8*)(                             \
                    base + (wm * 6 + mf) * 2048 + cl * 1024 + lane * 16);       \
        _Pragma("unroll") for (int pf = 0; pf < 4; ++pf)                        \
            _Pragma("unroll") for (int cl = 0; cl < 2; ++cl)                    \
                bf[pf * 2 + cl] = *(const short8*)(                             \
                    base + 24576 + cl * 8192 +                                  \
                    (wp * 64 + pf * 16 + lm) * 64 + lg * 16);                   \
        _Pragma("unroll") for (int cl = 0; cl < 2; ++cl)                        \
            _Pragma("unroll") for (int mf = 0; mf < 6; ++mf)                    \
                _Pragma("unroll") for (int pf = 0; pf < 4; ++pf)                \
                    acc[mf][pf] = __builtin_amdgcn_mfma_f32_16x16x32_bf16(      \
                        af[mf * 2 + cl], bf[pf * 2 + cl], acc[mf][pf], 0, 0, 0);\
    }

    STAGE(0, 0);
    __syncthreads();  // drains vmcnt(0) lgkmcnt(0) before barrier
#pragma unroll
    for (int kc = 0; kc < 9; ++kc) {
        const int b = kc & 1;
        if (kc < 8) STAGE(b ^ 1, kc + 1);
        COMPUTE(b);
        if (kc < 8) __syncthreads();
    }
#undef STAGE
#undef COMPUTE

    // epilogue: D col = lm (w), row = lg*4+r (m); + bias
    const int h0 = h0b + wp;
#pragma unroll
    for (int mf = 0; mf < 6; ++mf) {
#pragma unroll
        for (int r = 0; r < 4; ++r) {
            const int m = mg * 192 + wm * 96 + mf * 16 + lg * 4 + r;
            const int o = m & 63;
            const int ab2 = m >> 6;
            const float bo = bias[o];
            const int rowoff =
                ((n * 64 + o) * 192 + (h0 + 64 * (ab2 / 3))) * 192 + 64 * (ab2 % 3);
#pragma unroll
            for (int pf = 0; pf < 4; ++pf) {
                out[rowoff + pf * 16 + lm] = acc[mf][pf][r] + bo;
            }
        }
    }
}

// ---------------------------------------------------------------------------
// Fallback GEMM (round-1 validated, LDS-staged fp32) if ws too small for xT.
// ---------------------------------------------------------------------------
__global__ __launch_bounds__(256) void gemm_fallback(const float* __restrict__ x,
                                                     const unsigned short* __restrict__ Wt,
                                                     const float* __restrict__ bias,
                                                     float* __restrict__ out) {
    __shared__ unsigned short Xs[64][36];
    const int t = threadIdx.x;
    const int lane = t & 63;
    const int wv = t >> 6;
    const int pblk = blockIdx.x;
    const int mg = blockIdx.y;
    const int n = pblk >> 6;
    const int h0 = pblk & 63;
    const int wave_m0 = mg * 192 + wv * 48;
    const int lm = lane & 15;
    const int lg = lane >> 4;

    f32x4 acc[3][4] = {};
    const float* xb = x + n * 64 * 36864;
    const int w0s = t & 63;
    const int kq = (t >> 6) * 8;

    for (int c = 0; c < 18; ++c) {
        const int ab = c >> 1;
        const int al = ab / 3;
        const int be = ab % 3;
        const int ih = (c & 1) * 32;
        const int base = ih * 36864 + (h0 + 64 * al) * 192 + 64 * be + w0s;
#pragma unroll
        for (int s = 0; s < 8; ++s) {
            const int kp = kq + s;
            Xs[w0s][kp] = f2bf(xb[base + kp * 36864]);
        }
        __syncthreads();
        const int kb = c * 32 + lg * 8;
        short8 af[3];
#pragma unroll
        for (int mf = 0; mf < 3; ++mf)
            af[mf] = *(const short8*)(Wt + (wave_m0 + mf * 16 + lm) * 576 + kb);
        short8 bf[4];
#pragma unroll
        for (int pf = 0; pf < 4; ++pf) {
            union { short8 v; unsigned long long q[2]; } u;
            const unsigned long long* s8 =
                (const unsigned long long*)(&Xs[pf * 16 + lm][lg * 8]);
            u.q[0] = s8[0];
            u.q[1] = s8[1];
            bf[pf] = u.v;
        }
#pragma unroll
        for (int mf = 0; mf < 3; ++mf)
#pragma unroll
            for (int pf = 0; pf < 4; ++pf)
                acc[mf][pf] = __builtin_amdgcn_mfma_f32_16x16x32_bf16(
                    af[mf], bf[pf], acc[mf][pf], 0, 0, 0);
        __syncthreads();
    }

#pragma unroll
    for (int mf = 0; mf < 3; ++mf)
#pragma unroll
        for (int r = 0; r < 4; ++r) {
            const int m = wave_m0 + mf * 16 + lg * 4 + r;
            const int o = m & 63;
            const int ab2 = m >> 6;
            const float bo = bias[o];
            const int rowoff =
                ((n * 64 + o) * 192 + (h0 + 64 * (ab2 / 3))) * 192 + 64 * (ab2 % 3);
#pragma unroll
            for (int pf = 0; pf < 4; ++pf)
                out[rowoff + pf * 16 + lm] = acc[mf][pf][r] + bo;
        }
}

// ---------------------------------------------------------------------------
extern "C" void kernel_launch(void* const* d_in, const int* in_sizes, int n_in,
                              void* d_out, int out_size, void* d_ws, size_t ws_size,
                              hipStream_t stream) {
    (void)in_sizes; (void)n_in; (void)out_size;
    const float* x = (const float*)d_in[0];
    const float* W = (const float*)d_in[1];
    const float* bias = (const float*)d_in[2];
    const float* u0 = (const float*)d_in[3];
    float* out = (float*)d_out;

    float* Fm = (float*)d_ws;
    unsigned short* Wtf = (unsigned short*)((char*)d_ws + WTF_OFF);
    unsigned short* WtOld = (unsigned short*)((char*)d_ws + WTOLD_OFF);
    unsigned short* xT = (unsigned short*)((char*)d_ws + XT_OFF);

    const bool big_ws = (ws_size >= WS_NEEDED);

    if (big_ws) {
        fmconv_kernel<<<5 + 18432, 512, 0, stream>>>(W, u0, x, Fm, xT);
        wbuild_kernel<<<16, 256, 0, stream>>>(Fm, Wtf, WtOld);
        gemm4_kernel<<<1536, 256, 0, stream>>>(xT, Wtf, bias, out);
    } else {
        fmconv_kernel<<<5, 512, 0, stream>>>(W, u0, x, Fm, xT);
        wbuild_kernel<<<16, 256, 0, stream>>>(Fm, Wtf, WtOld);
        dim3 g(1024, 3, 1);
        gemm_fallback<<<g, 256, 0, stream>>>(x, WtOld, bias, out);
    }
}

// Round 5
// 146.150 us; speedup vs baseline: 1.7329x; 1.0780x over previous
//
#include <hip/hip_runtime.h>

typedef __attribute__((ext_vector_type(8))) short short8;
typedef __attribute__((ext_vector_type(4))) float f32x4;
typedef __attribute__((ext_vector_type(4))) float float4v;

__device__ __forceinline__ unsigned short f2bf(float f) {
    unsigned int u = __float_as_uint(f);
    u += 0x7fffu + ((u >> 16) & 1u);
    return (unsigned short)(u >> 16);
}

__device__ __forceinline__ float wavesum(float x) {
#pragma unroll
    for (int m = 1; m < 64; m <<= 1) x += __shfl_xor(x, m);
    return x;
}

// dot(row[0..63], y-distributed-one-per-lane) via readlane broadcasts.
__device__ __forceinline__ float matvec64(const float* row, float y) {
    float ac[8] = {0.f, 0.f, 0.f, 0.f, 0.f, 0.f, 0.f, 0.f};
#pragma unroll
    for (int j = 0; j < 64; ++j) {
        const float yj =
            __uint_as_float(__builtin_amdgcn_readlane(__float_as_uint(y), j));
        ac[j & 7] = fmaf(row[j], yj, ac[j & 7]);
    }
    return ((ac[0] + ac[1]) + (ac[2] + ac[3])) + ((ac[4] + ac[5]) + (ac[6] + ac[7]));
}

// async 16B global -> LDS (linear dest: wave-uniform base + lane*16)
__device__ __forceinline__ void gload16(const void* g, void* l) {
    __builtin_amdgcn_global_load_lds(
        (const __attribute__((address_space(1))) unsigned int*)g,
        (__attribute__((address_space(3))) unsigned int*)l, 16, 0, 0);
}

#define WTF_OFF       81920
#define WTOLD_OFF     745472
#define XT_OFF        1441792
#define WS_NEEDED     76939264UL

// ---------------------------------------------------------------------------
// Fused: blocks 0..4 = fm (register power iteration + LDS Taylor);
//        blocks 5..1540 = pipelined x fp32 -> bf16 transpose (12 tiles/block)
//        to xT[n][h][half][w][c32].
// ---------------------------------------------------------------------------
__global__ __launch_bounds__(512) void fmconv_kernel(const float* __restrict__ W,
                                                     const float* __restrict__ u0,
                                                     const float* __restrict__ x,
                                                     float* __restrict__ FmOut,
                                                     unsigned short* __restrict__ xT) {
    __shared__ __align__(16) char smem[35840];
    const int t = threadIdx.x;

    if (blockIdx.x >= 5) {
        // ---- convert path: block = (n, hpair); 12 tiles = 2h x 2half x 3wb.
        // Per tile: phase1 float4 load -> LDS (ping-pong), bar, phase2 pack+store.
        // Next tile's load issued before the barrier (latency hidden).
        float (*L0)[66] = (float (*)[66])smem;              // 8448 B
        float (*L1)[66] = (float (*)[66])(smem + 8448);     // 8448 B
        const int bb = blockIdx.x - 5;     // 0..1535
        const int n = bb / 96;
        const int hpair = bb % 96;
        const int c  = t >> 4;             // 0..31
        const int w4 = (t & 15) * 4;       // 0..60
        const int w2 = t >> 3;             // 0..63
        const int c4 = (t & 7) * 4;        // 0..28

#define XADDR(I)                                                                \
    (x + ((size_t)((n * 64 + ((I) & 1) * 32 + c) * 192 +                        \
                   (hpair * 2 + (I) / 6))) * 192 + (((I) >> 1) % 3) * 64 + w4)

        float4v r = *(const float4v*)XADDR(0);
        float4v rn;
#pragma unroll
        for (int i = 0; i < 12; ++i) {
            float (*L)[66] = (i & 1) ? L1 : L0;
            if (i < 11) rn = *(const float4v*)XADDR(i + 1);
            L[c][w4 + 0] = r[0];
            L[c][w4 + 1] = r[1];
            L[c][w4 + 2] = r[2];
            L[c][w4 + 3] = r[3];
            __syncthreads();
            union { unsigned short u[4]; unsigned long long q; } pk;
#pragma unroll
            for (int k = 0; k < 4; ++k) pk.u[k] = f2bf(L[c4 + k][w2]);
            const int half = i & 1;
            const int wb = (i >> 1) % 3;
            const int dh = i / 6;
            const size_t tilebase =
                ((size_t)(((n * 192 + hpair * 2 + dh) * 2 + half))) * 6144 + wb * 2048;
            *(unsigned long long*)(xT + tilebase + w2 * 32 + c4) = pk.q;
            r = rn;
        }
#undef XADDR
        return;
    }

    // ---- fm path (unchanged, validated) ----
    float (*A)[68]  = (float (*)[68])smem;
    float (*Bu)[68] = (float (*)[68])(smem + 17408);
    float* sigP = (float*)(smem + 34816);

    const int n = blockIdx.x;  // 0..4
    {
        const int i = t >> 3;
        const int j0 = (t & 7) * 8;
#pragma unroll
        for (int k = 0; k < 8; ++k) {
            const int j = j0 + k;
            const float wij = W[(i * 64 + j) * 5 + n];
            const float wji = W[(j * 64 + i) * 5 + n];
            A[i][j] = 0.5f * (wij - wji);
        }
    }
    __syncthreads();

    if (t < 64) {
        float row[64];
#pragma unroll
        for (int q = 0; q < 16; ++q)
            *(float4v*)&row[q * 4] = *(const float4v*)(&A[t][q * 4]);
        float uv = u0[n * 64 + t];
        uv = uv / (sqrtf(wavesum(uv * uv)) + 1e-12f);
        float vv = 0.0f;
        for (int it = 0; it < 50; ++it) {
            const float w = matvec64(row, uv);
            vv = w / (sqrtf(wavesum(w * w)) + 1e-12f);
            const float z = matvec64(row, vv);
            uv = -z / (sqrtf(wavesum(z * z)) + 1e-12f);
        }
        const float w2 = matvec64(row, uv);
        const float sig = wavesum(vv * w2);
        if (t == 0) *sigP = sig;
    }
    __syncthreads();

    const float sig = *sigP;
    {
        const int i = t >> 3;
        const int j0 = (t & 7) * 8;
#pragma unroll
        for (int k = 0; k < 8; ++k) A[i][j0 + k] = A[i][j0 + k] / sig;
    }
    __syncthreads();

    const int r = t >> 3;
    const int c0 = (t & 7) * 8;
    float fm[8];
#pragma unroll
    for (int k = 0; k < 8; ++k) fm[k] = A[r][c0 + k];

    const float* curbase = &A[0][0];
    for (int term = 2; term <= 10; ++term) {
        float nx[8];
#pragma unroll
        for (int k = 0; k < 8; ++k) nx[k] = 0.0f;
        for (int j = 0; j < 64; ++j) {
            const float crj = curbase[r * 68 + j];
            const float* arow = &A[j][c0];
#pragma unroll
            for (int k = 0; k < 8; ++k) nx[k] += crj * arow[k];
        }
        const float ft = (float)term;
#pragma unroll
        for (int k = 0; k < 8; ++k) {
            nx[k] = nx[k] / ft;
            fm[k] += nx[k];
        }
        __syncthreads();
#pragma unroll
        for (int k = 0; k < 8; ++k) Bu[r][c0 + k] = nx[k];
        __syncthreads();
        curbase = &Bu[0][0];
    }
#pragma unroll
    for (int k = 0; k < 8; ++k)
        FmOut[n * 4096 + r * 64 + c0 + k] = fm[k] + ((r == (c0 + k)) ? 1.0f : 0.0f);
}

// ---------------------------------------------------------------------------
// wbuild: Fm -> 3x3 real-ifft -> folded weight; Wtf (16x16 A-frag order) and
// WtOld ([m][kap]) for the fallback path.
// ---------------------------------------------------------------------------
__global__ __launch_bounds__(256) void wbuild_kernel(const float* __restrict__ Fm,
                                                     unsigned short* __restrict__ Wtf,
                                                     unsigned short* __restrict__ WtOld) {
    const int tg = blockIdx.x * 256 + threadIdx.x;  // 0..4095
    const int o = tg >> 6;
    const int i = tg & 63;
    float f[5];
#pragma unroll
    for (int nn = 0; nn < 5; ++nn) f[nn] = Fm[nn * 4096 + o * 64 + i];
    const int idx[3][3] = {{0, 1, 1}, {2, 3, 4}, {2, 4, 3}};
    float Kk[3][3];
#pragma unroll
    for (int u = 0; u < 3; ++u) {
#pragma unroll
        for (int v = 0; v < 3; ++v) {
            float s = 0.0f;
#pragma unroll
            for (int p = 0; p < 3; ++p) {
#pragma unroll
                for (int q = 0; q < 3; ++q) {
                    const int m = (p * u + q * v) % 3;
                    s += f[idx[p][q]] * ((m == 0) ? 1.0f : -0.5f);
                }
            }
            Kk[u][v] = s * (1.0f / 9.0f);
        }
    }
#pragma unroll
    for (int a = 0; a < 3; ++a) {
#pragma unroll
        for (int b = 0; b < 3; ++b) {
            const int m = (a * 3 + b) * 64 + o;
#pragma unroll
            for (int al = 0; al < 3; ++al) {
#pragma unroll
                for (int be = 0; be < 3; ++be) {
                    const int kh = (al - a + 4) % 3;
                    const int kw = (be - b + 4) % 3;
                    const unsigned short bf = f2bf(Kk[kh][kw]);
                    const int kap = (al * 3 + be) * 64 + i;
                    WtOld[m * 576 + kap] = bf;
                    const int MF = m >> 4, lm = m & 15;
                    const int cc = kap >> 5, lg = (kap >> 3) & 3, j = kap & 7;
                    Wtf[MF * 9216 + cc * 512 + (lg * 16 + lm) * 8 + j] = bf;
                }
            }
        }
    }
}

// ---------------------------------------------------------------------------
// gemm4: LDS double-buffered. Block = 192m x 128p, 4 waves (2wm x 2wp),
// wave = 96m x 64p. K-chunk = 64 kap. LDS 2 x (A 24KB + B 16KB) = 80KB.
// Staged via global_load_lds x16B. (Unchanged from round 4, validated.)
// ---------------------------------------------------------------------------
__global__ __launch_bounds__(256, 2) void gemm4_kernel(
    const unsigned short* __restrict__ xT, const unsigned short* __restrict__ Wtf,
    const float* __restrict__ bias, float* __restrict__ out) {
    __shared__ __align__(16) char smem[81920];
    const int t = threadIdx.x;
    const int lane = t & 63;
    const int wv = t >> 6;
    const int wm = wv >> 1;
    const int wp = wv & 1;
    const int lm = lane & 15;
    const int lg = lane >> 4;

    const int orig = blockIdx.x;
    const int swz = (orig & 7) * 192 + (orig >> 3);
    const int mg = swz % 3;
    const int panel = swz / 3;
    const int n = panel >> 5;
    const int h0b = (panel & 31) * 2;

    f32x4 acc[6][4] = {};

#define STAGE(BUF, KC)                                                          \
    {                                                                           \
        const int al_ = (KC) / 3, be_ = (KC) - 3 * ((KC) / 3);                  \
        _Pragma("unroll") for (int it = 0; it < 10; ++it) {                     \
            char* ldsb = smem + (BUF) * 40960 + it * 4096 + wv * 1024;          \
            const unsigned short* src;                                          \
            if (it < 6) {                                                       \
                const int e = it * 2048 + t * 8;                                \
                const int mfL = e >> 10;                                        \
                const int rem = e & 1023;                                       \
                src = Wtf + (mg * 12 + mfL) * 9216 + (KC) * 1024 + rem;         \
            } else {                                                            \
                const int e = (it - 6) * 2048 + t * 8;                          \
                const int ccL = e >> 12;                                        \
                const int rem = e & 4095;                                       \
                const int p_ = rem >> 5;                                        \
                const int c_ = rem & 31;                                        \
                const int h_ = h0b + (p_ >> 6) + 64 * al_;                      \
                const int w_ = be_ * 64 + (p_ & 63);                            \
                src = xT + ((size_t)((n * 192 + h_) * 2 + ccL)) * 6144 +        \
                      w_ * 32 + c_;                                             \
            }                                                                   \
            gload16(src, ldsb);                                                 \
        }                                                                       \
    }

#define COMPUTE(BUF)                                                            \
    {                                                                           \
        const char* base = smem + (BUF) * 40960;                                \
        short8 af[12];                                                          \
        short8 bf[8];                                                           \
        _Pragma("unroll") for (int mf = 0; mf < 6; ++mf)                        \
            _Pragma("unroll") for (int cl = 0; cl < 2; ++cl)                    \
                af[mf * 2 + cl] = *(const short8*)(                             \
                    base + (wm * 6 + mf) * 2048 + cl * 1024 + lane * 16);       \
        _Pragma("unroll") for (int pf = 0; pf < 4; ++pf)                        \
            _Pragma("unroll") for (int cl = 0; cl < 2; ++cl)                    \
                bf[pf * 2 + cl] = *(const short8*)(                             \
                    base + 24576 + cl * 8192 +                                  \
                    (wp * 64 + pf * 16 + lm) * 64 + lg * 16);                   \
        _Pragma("unroll") for (int cl = 0; cl < 2; ++cl)                        \
            _Pragma("unroll") for (int mf = 0; mf < 6; ++mf)                    \
                _Pragma("unroll") for (int pf = 0; pf < 4; ++pf)                \
                    acc[mf][pf] = __builtin_amdgcn_mfma_f32_16x16x32_bf16(      \
                        af[mf * 2 + cl], bf[pf * 2 + cl], acc[mf][pf], 0, 0, 0);\
    }

    STAGE(0, 0);
    __syncthreads();
#pragma unroll
    for (int kc = 0; kc < 9; ++kc) {
        const int b = kc & 1;
        if (kc < 8) STAGE(b ^ 1, kc + 1);
        COMPUTE(b);
        if (kc < 8) __syncthreads();
    }
#undef STAGE
#undef COMPUTE

    const int h0 = h0b + wp;
#pragma unroll
    for (int mf = 0; mf < 6; ++mf) {
#pragma unroll
        for (int r = 0; r < 4; ++r) {
            const int m = mg * 192 + wm * 96 + mf * 16 + lg * 4 + r;
            const int o = m & 63;
            const int ab2 = m >> 6;
            const float bo = bias[o];
            const int rowoff =
                ((n * 64 + o) * 192 + (h0 + 64 * (ab2 / 3))) * 192 + 64 * (ab2 % 3);
#pragma unroll
            for (int pf = 0; pf < 4; ++pf) {
                out[rowoff + pf * 16 + lm] = acc[mf][pf][r] + bo;
            }
        }
    }
}

// ---------------------------------------------------------------------------
// Fallback GEMM (round-1 validated, LDS-staged fp32) if ws too small for xT.
// ---------------------------------------------------------------------------
__global__ __launch_bounds__(256) void gemm_fallback(const float* __restrict__ x,
                                                     const unsigned short* __restrict__ Wt,
                                                     const float* __restrict__ bias,
                                                     float* __restrict__ out) {
    __shared__ unsigned short Xs[64][36];
    const int t = threadIdx.x;
    const int lane = t & 63;
    const int wv = t >> 6;
    const int pblk = blockIdx.x;
    const int mg = blockIdx.y;
    const int n = pblk >> 6;
    const int h0 = pblk & 63;
    const int wave_m0 = mg * 192 + wv * 48;
    const int lm = lane & 15;
    const int lg = lane >> 4;

    f32x4 acc[3][4] = {};
    const float* xb = x + n * 64 * 36864;
    const int w0s = t & 63;
    const int kq = (t >> 6) * 8;

    for (int c = 0; c < 18; ++c) {
        const int ab = c >> 1;
        const int al = ab / 3;
        const int be = ab % 3;
        const int ih = (c & 1) * 32;
        const int base = ih * 36864 + (h0 + 64 * al) * 192 + 64 * be + w0s;
#pragma unroll
        for (int s = 0; s < 8; ++s) {
            const int kp = kq + s;
            Xs[w0s][kp] = f2bf(xb[base + kp * 36864]);
        }
        __syncthreads();
        const int kb = c * 32 + lg * 8;
        short8 af[3];
#pragma unroll
        for (int mf = 0; mf < 3; ++mf)
            af[mf] = *(const short8*)(Wt + (wave_m0 + mf * 16 + lm) * 576 + kb);
        short8 bf[4];
#pragma unroll
        for (int pf = 0; pf < 4; ++pf) {
            union { short8 v; unsigned long long q[2]; } u;
            const unsigned long long* s8 =
                (const unsigned long long*)(&Xs[pf * 16 + lm][lg * 8]);
            u.q[0] = s8[0];
            u.q[1] = s8[1];
            bf[pf] = u.v;
        }
#pragma unroll
        for (int mf = 0; mf < 3; ++mf)
#pragma unroll
            for (int pf = 0; pf < 4; ++pf)
                acc[mf][pf] = __builtin_amdgcn_mfma_f32_16x16x32_bf16(
                    af[mf], bf[pf], acc[mf][pf], 0, 0, 0);
        __syncthreads();
    }

#pragma unroll
    for (int mf = 0; mf < 3; ++mf)
#pragma unroll
        for (int r = 0; r < 4; ++r) {
            const int m = wave_m0 + mf * 16 + lg * 4 + r;
            const int o = m & 63;
            const int ab2 = m >> 6;
            const float bo = bias[o];
            const int rowoff =
                ((n * 64 + o) * 192 + (h0 + 64 * (ab2 / 3))) * 192 + 64 * (ab2 % 3);
#pragma unroll
            for (int pf = 0; pf < 4; ++pf)
                out[rowoff + pf * 16 + lm] = acc[mf][pf][r] + bo;
        }
}

// ---------------------------------------------------------------------------
extern "C" void kernel_launch(void* const* d_in, const int* in_sizes, int n_in,
                              void* d_out, int out_size, void* d_ws, size_t ws_size,
                              hipStream_t stream) {
    (void)in_sizes; (void)n_in; (void)out_size;
    const float* x = (const float*)d_in[0];
    const float* W = (const float*)d_in[1];
    const float* bias = (const float*)d_in[2];
    const float* u0 = (const float*)d_in[3];
    float* out = (float*)d_out;

    float* Fm = (float*)d_ws;
    unsigned short* Wtf = (unsigned short*)((char*)d_ws + WTF_OFF);
    unsigned short* WtOld = (unsigned short*)((char*)d_ws + WTOLD_OFF);
    unsigned short* xT = (unsigned short*)((char*)d_ws + XT_OFF);

    const bool big_ws = (ws_size >= WS_NEEDED);

    if (big_ws) {
        fmconv_kernel<<<5 + 1536, 512, 0, stream>>>(W, u0, x, Fm, xT);
        wbuild_kernel<<<16, 256, 0, stream>>>(Fm, Wtf, WtOld);
        gemm4_kernel<<<1536, 256, 0, stream>>>(xT, Wtf, bias, out);
    } else {
        fmconv_kernel<<<5, 512, 0, stream>>>(W, u0, x, Fm, xT);
        wbuild_kernel<<<16, 256, 0, stream>>>(Fm, Wtf, WtOld);
        dim3 g(1024, 3, 1);
        gemm_fallback<<<g, 256, 0, stream>>>(x, WtOld, bias, out);
    }
}

// Round 6
// 112.792 us; speedup vs baseline: 2.2454x; 1.2957x over previous
//
#include <hip/hip_runtime.h>

typedef __attribute__((ext_vector_type(8))) short short8;
typedef __attribute__((ext_vector_type(4))) float f32x4;
typedef __attribute__((ext_vector_type(4))) float float4v;
typedef __attribute__((ext_vector_type(4))) unsigned int u32x4;

__device__ __forceinline__ unsigned short f2bf(float f) {
    unsigned int u = __float_as_uint(f);
    u += 0x7fffu + ((u >> 16) & 1u);
    return (unsigned short)(u >> 16);
}

__device__ __forceinline__ float wavesum(float x) {
#pragma unroll
    for (int m = 1; m < 64; m <<= 1) x += __shfl_xor(x, m);
    return x;
}

__device__ __forceinline__ float wavemax(float x) {
#pragma unroll
    for (int m = 1; m < 64; m <<= 1) x = fmaxf(x, __shfl_xor(x, m));
    return x;
}

// dot(row[0..63], y-distributed-one-per-lane) via readlane broadcasts.
__device__ __forceinline__ float matvec64(const float* row, float y) {
    float ac[8] = {0.f, 0.f, 0.f, 0.f, 0.f, 0.f, 0.f, 0.f};
#pragma unroll
    for (int j = 0; j < 64; ++j) {
        const float yj =
            __uint_as_float(__builtin_amdgcn_readlane(__float_as_uint(y), j));
        ac[j & 7] = fmaf(row[j], yj, ac[j & 7]);
    }
    return ((ac[0] + ac[1]) + (ac[2] + ac[3])) + ((ac[4] + ac[5]) + (ac[6] + ac[7]));
}

// async 16B global -> LDS (linear dest: wave-uniform base + lane*16)
__device__ __forceinline__ void gload16(const void* g, void* l) {
    __builtin_amdgcn_global_load_lds(
        (const __attribute__((address_space(1))) unsigned int*)g,
        (__attribute__((address_space(3))) unsigned int*)l, 16, 0, 0);
}

#define WTF_OFF       81920
#define WTOLD_OFF     745472
#define XT_OFF        1441792
#define WS_NEEDED     76939264UL

// fm LDS layout (bytes):
#define FM_AFP   0        // fp32 [64][68] = 17408
#define FM_R0    17408    // fp32 [64][68]
#define FM_R1    34816    // fp32 [64][68]
#define FM_SLOT  52224    // 3 slots x 4096 half (8192 B each) = 24576
#define FM_RED   76800    // 4 float wave-max + sigma
#define FM_SMEM  76928

// ---------------------------------------------------------------------------
// One 64x64x64 matmul on 4 waves (t<256), single-bf16 operands, fp32 acc.
// OUT = (src @ Bfrag(bfSrcSlot)) * (1/maxabs); writes dst fp32 rm [64][68]
// and optionally the B-fragment bf16 layout of OUT into bfDstSlot.
// B-frag layout (validated gemm convention): element (k,nn) at half-index
// ((k>>5)*4 + nn>>4)*64*8 + (((k&31)>>3)*16 + (nn&15))*8 + (k&7).
// ---------------------------------------------------------------------------
__device__ __forceinline__ void fm_matmul_sb(char* sm, int srcOff, int bfSrcSlot,
                                             int dstOff, int bfDstSlot, int t) {
    const float* src = (const float*)(sm + srcOff);
    const unsigned short* bfS =
        (const unsigned short*)(sm + FM_SLOT) + bfSrcSlot * 4096;
    float* dst = (float*)(sm + dstOff);
    float* redf = (float*)(sm + FM_RED);
    const int lane = t & 63;
    const int wv = t >> 6;
    const int lm = lane & 15, lg = lane >> 4;
    f32x4 acc[4] = {};
    if (t < 256) {
#pragma unroll
        for (int kk = 0; kk < 2; ++kk) {
            const float* ap = src + (16 * wv + lm) * 68 + kk * 32 + lg * 8;
            const f32x4 a0 = *(const f32x4*)ap;
            const f32x4 a1 = *(const f32x4*)(ap + 4);
            short8 ah;
#pragma unroll
            for (int j = 0; j < 4; ++j) {
                ah[j] = (short)f2bf(a0[j]);
                ah[j + 4] = (short)f2bf(a1[j]);
            }
#pragma unroll
            for (int cf = 0; cf < 4; ++cf) {
                const short8 b =
                    *(const short8*)(bfS + ((kk * 4 + cf) * 64 + lane) * 8);
                acc[cf] = __builtin_amdgcn_mfma_f32_16x16x32_bf16(ah, b, acc[cf],
                                                                  0, 0, 0);
            }
        }
        float mx = 0.0f;
#pragma unroll
        for (int cf = 0; cf < 4; ++cf)
#pragma unroll
            for (int r = 0; r < 4; ++r) mx = fmaxf(mx, fabsf(acc[cf][r]));
        mx = wavemax(mx);
        if (lane == 0) redf[wv] = mx;
    }
    __syncthreads();
    if (t < 256) {
        const float g = fmaxf(fmaxf(redf[0], redf[1]), fmaxf(redf[2], redf[3]));
        const float sc = 1.0f / g;
        unsigned short* bfD = (unsigned short*)(sm + FM_SLOT) + bfDstSlot * 4096;
#pragma unroll
        for (int cf = 0; cf < 4; ++cf) {
#pragma unroll
            for (int r = 0; r < 4; ++r) {
                const int k = 16 * wv + 4 * lg + r;
                const int nn = 16 * cf + lm;
                const float v = acc[cf][r] * sc;
                dst[k * 68 + nn] = v;
                if (bfDstSlot >= 0)
                    bfD[(((k >> 5) * 4 + cf) * 64 + ((k & 31) >> 3) * 16 + lm) * 8 +
                        (k & 7)] = f2bf(v);
            }
        }
    }
    __syncthreads();
}

// ---------------------------------------------------------------------------
// Fused: blocks 0..4 = fm (matrix-power sigma + MFMA bf16x3 Taylor);
//        blocks 5..1540 = pipelined x fp32 -> bf16 transpose (12 tiles/block).
// ---------------------------------------------------------------------------
__global__ __launch_bounds__(512) void fmconv_kernel(const float* __restrict__ W,
                                                     const float* __restrict__ u0,
                                                     const float* __restrict__ x,
                                                     float* __restrict__ FmOut,
                                                     unsigned short* __restrict__ xT) {
    __shared__ __align__(16) char smem[FM_SMEM];
    const int t = threadIdx.x;

    if (blockIdx.x >= 5) {
        // ---- convert path (unchanged, validated) ----
        float (*L0)[66] = (float (*)[66])smem;
        float (*L1)[66] = (float (*)[66])(smem + 8448);
        const int bb = blockIdx.x - 5;
        const int n = bb / 96;
        const int hpair = bb % 96;
        const int c = t >> 4;
        const int w4 = (t & 15) * 4;
        const int w2 = t >> 3;
        const int c4 = (t & 7) * 4;

#define XADDR(I)                                                                \
    (x + ((size_t)((n * 64 + ((I) & 1) * 32 + c) * 192 +                        \
                   (hpair * 2 + (I) / 6))) * 192 + (((I) >> 1) % 3) * 64 + w4)

        float4v r = *(const float4v*)XADDR(0);
        float4v rn;
#pragma unroll
        for (int i = 0; i < 12; ++i) {
            float (*L)[66] = (i & 1) ? L1 : L0;
            if (i < 11) rn = *(const float4v*)XADDR(i + 1);
            L[c][w4 + 0] = r[0];
            L[c][w4 + 1] = r[1];
            L[c][w4 + 2] = r[2];
            L[c][w4 + 3] = r[3];
            __syncthreads();
            union { unsigned short u[4]; unsigned long long q; } pk;
#pragma unroll
            for (int k = 0; k < 4; ++k) pk.u[k] = f2bf(L[c4 + k][w2]);
            const int half = i & 1;
            const int wb = (i >> 1) % 3;
            const int dh = i / 6;
            const size_t tilebase =
                ((size_t)(((n * 192 + hpair * 2 + dh) * 2 + half))) * 6144 + wb * 2048;
            *(unsigned long long*)(xT + tilebase + w2 * 32 + c4) = pk.q;
            r = rn;
        }
#undef XADDR
        return;
    }

    // ---- fm path ----
    float* Afp = (float*)(smem + FM_AFP);
    float* R0f = (float*)(smem + FM_R0);
    float* R1f = (float*)(smem + FM_R1);
    float* redf = (float*)(smem + FM_RED);
    float* sigP = redf + 4;
    const int n = blockIdx.x;
    const int lane = t & 63;
    const int wv = t >> 6;
    const int lm = lane & 15, lg = lane >> 4;

    // stage A = 0.5*(W - W^T) into Afp (all 512 threads)
    {
        const int i = t >> 3;
        const int j0 = (t & 7) * 8;
#pragma unroll
        for (int k = 0; k < 8; ++k) {
            const int j = j0 + k;
            const float wij = W[(i * 64 + j) * 5 + n];
            const float wji = W[(j * 64 + i) * 5 + n];
            Afp[i * 68 + j] = 0.5f * (wij - wji);
        }
    }
    __syncthreads();

    // bfA (slot 0): B-frag bf16 layout of A
    if (t < 256) {
        unsigned short* s0 = (unsigned short*)(smem + FM_SLOT);
#pragma unroll
        for (int cf = 0; cf < 4; ++cf) {
#pragma unroll
            for (int r = 0; r < 4; ++r) {
                const int k = 16 * wv + 4 * lg + r;
                const int nn = 16 * cf + lm;
                s0[(((k >> 5) * 4 + cf) * 64 + ((k & 31) >> 3) * 16 + lm) * 8 +
                   (k & 7)] = f2bf(Afp[k * 68 + nn]);
            }
        }
    }
    __syncthreads();

    // matrix-power chain: M=A^2; M^2,4,8,16,32; M^48=M32@M16; M^49=M48@M
    fm_matmul_sb(smem, FM_AFP, 0, FM_R0, 1, t);  // M    -> R0, bfM   = slot1
    fm_matmul_sb(smem, FM_R0, 1, FM_R1, 2, t);   // M2   -> R1, bfM2  = slot2
    fm_matmul_sb(smem, FM_R1, 2, FM_R0, 0, t);   // M4   -> R0, bfM4  = slot0
    fm_matmul_sb(smem, FM_R0, 0, FM_R1, 2, t);   // M8   -> R1, bfM8  = slot2
    fm_matmul_sb(smem, FM_R1, 2, FM_R0, 0, t);   // M16  -> R0, bfM16 = slot0
    fm_matmul_sb(smem, FM_R0, 0, FM_R1, -1, t);  // M32  -> R1
    fm_matmul_sb(smem, FM_R1, 0, FM_R0, -1, t);  // M48 = M32@M16 -> R0
    fm_matmul_sb(smem, FM_R0, 1, FM_R1, -1, t);  // M49 = M48@M   -> R1

    // sigma: u49 ~ M49 u0n; v = l2n(A u49); u50 = l2n(A^T v); sig = v^T A u50
    if (t < 64) {
        float row[64];
#pragma unroll
        for (int q = 0; q < 16; ++q)
            *(f32x4*)&row[q * 4] = *(const f32x4*)&R1f[t * 68 + q * 4];
        float u = u0[n * 64 + t];
        u = u / (sqrtf(wavesum(u * u)) + 1e-12f);
        const float w = matvec64(row, u);  // direction of u49 (scale irrelevant)
#pragma unroll
        for (int q = 0; q < 16; ++q)
            *(f32x4*)&row[q * 4] = *(const f32x4*)&Afp[t * 68 + q * 4];
        const float tt = matvec64(row, w);                  // ~ A u49
        const float v = tt / (sqrtf(wavesum(tt * tt)) + 1e-12f);
        const float s = matvec64(row, v);                   // A v
        const float u50 = -s / (sqrtf(wavesum(s * s)) + 1e-12f);  // l2n(A^T v)
        const float t2 = matvec64(row, u50);                // A u50
        const float sig = wavesum(v * t2);
        if (t == 0) *sigP = sig;
    }
    __syncthreads();

    // An prep: R0 = An fp32; Anpk (packed h|l<<16) in slots 0-1; Fm init = An
    const float inv_sig = 1.0f / (*sigP);
    float Fm[4][4];
    if (t < 256) {
        unsigned int* Anpk = (unsigned int*)(smem + FM_SLOT);
#pragma unroll
        for (int cf = 0; cf < 4; ++cf) {
#pragma unroll
            for (int r = 0; r < 4; ++r) {
                const int k = 16 * wv + 4 * lg + r;
                const int nn = 16 * cf + lm;
                const float v = Afp[k * 68 + nn] * inv_sig;
                R0f[k * 68 + nn] = v;
                const unsigned int ph = f2bf(v);
                const float hf = __uint_as_float(ph << 16);
                const unsigned int pl = f2bf(v - hf);
                Anpk[(((k >> 5) * 4 + cf) * 64 + ((k & 31) >> 3) * 16 + lm) * 8 +
                     (k & 7)] = ph | (pl << 16);
                Fm[cf][r] = v;
            }
        }
    }
    __syncthreads();

    // Taylor terms 2..10: curr = (curr @ An)/i (bf16x3), Fm += curr
    for (int term = 2; term <= 10; ++term) {
        f32x4 acc[4] = {};
        if (t < 256) {
            const unsigned int* Anpk = (const unsigned int*)(smem + FM_SLOT);
#pragma unroll
            for (int kk = 0; kk < 2; ++kk) {
                const float* ap = R0f + (16 * wv + lm) * 68 + kk * 32 + lg * 8;
                const f32x4 a0 = *(const f32x4*)ap;
                const f32x4 a1 = *(const f32x4*)(ap + 4);
                short8 ah, al;
#pragma unroll
                for (int j = 0; j < 4; ++j) {
                    const unsigned int h0 = f2bf(a0[j]);
                    ah[j] = (short)h0;
                    al[j] = (short)f2bf(a0[j] - __uint_as_float(h0 << 16));
                    const unsigned int h1 = f2bf(a1[j]);
                    ah[j + 4] = (short)h1;
                    al[j + 4] = (short)f2bf(a1[j] - __uint_as_float(h1 << 16));
                }
#pragma unroll
                for (int cf = 0; cf < 4; ++cf) {
                    const unsigned int* pp = Anpk + ((kk * 4 + cf) * 64 + lane) * 8;
                    const u32x4 p0 = *(const u32x4*)pp;
                    const u32x4 p1 = *(const u32x4*)(pp + 4);
                    short8 bh, bl;
#pragma unroll
                    for (int j = 0; j < 4; ++j) {
                        bh[j] = (short)(p0[j] & 0xffffu);
                        bl[j] = (short)(p0[j] >> 16);
                        bh[j + 4] = (short)(p1[j] & 0xffffu);
                        bl[j + 4] = (short)(p1[j] >> 16);
                    }
                    acc[cf] = __builtin_amdgcn_mfma_f32_16x16x32_bf16(ah, bh,
                                                                      acc[cf], 0, 0, 0);
                    acc[cf] = __builtin_amdgcn_mfma_f32_16x16x32_bf16(ah, bl,
                                                                      acc[cf], 0, 0, 0);
                    acc[cf] = __builtin_amdgcn_mfma_f32_16x16x32_bf16(al, bh,
                                                                      acc[cf], 0, 0, 0);
                }
            }
        }
        __syncthreads();  // all reads of R0f done
        if (t < 256) {
            const float sc = 1.0f / (float)term;
#pragma unroll
            for (int cf = 0; cf < 4; ++cf) {
#pragma unroll
                for (int r = 0; r < 4; ++r) {
                    const int k = 16 * wv + 4 * lg + r;
                    const int nn = 16 * cf + lm;
                    const float v = acc[cf][r] * sc;
                    Fm[cf][r] += v;
                    if (term < 10) R0f[k * 68 + nn] = v;
                }
            }
        }
        __syncthreads();
    }

    if (t < 256) {
#pragma unroll
        for (int cf = 0; cf < 4; ++cf) {
#pragma unroll
            for (int r = 0; r < 4; ++r) {
                const int k = 16 * wv + 4 * lg + r;
                const int nn = 16 * cf + lm;
                FmOut[n * 4096 + k * 64 + nn] = Fm[cf][r] + ((k == nn) ? 1.0f : 0.0f);
            }
        }
    }
}

// ---------------------------------------------------------------------------
// wbuild: Fm -> 3x3 real-ifft -> folded weight; Wtf (16x16 A-frag order) and
// WtOld ([m][kap]) for the fallback path. (Unchanged.)
// ---------------------------------------------------------------------------
__global__ __launch_bounds__(256) void wbuild_kernel(const float* __restrict__ Fm,
                                                     unsigned short* __restrict__ Wtf,
                                                     unsigned short* __restrict__ WtOld) {
    const int tg = blockIdx.x * 256 + threadIdx.x;
    const int o = tg >> 6;
    const int i = tg & 63;
    float f[5];
#pragma unroll
    for (int nn = 0; nn < 5; ++nn) f[nn] = Fm[nn * 4096 + o * 64 + i];
    const int idx[3][3] = {{0, 1, 1}, {2, 3, 4}, {2, 4, 3}};
    float Kk[3][3];
#pragma unroll
    for (int u = 0; u < 3; ++u) {
#pragma unroll
        for (int v = 0; v < 3; ++v) {
            float s = 0.0f;
#pragma unroll
            for (int p = 0; p < 3; ++p) {
#pragma unroll
                for (int q = 0; q < 3; ++q) {
                    const int m = (p * u + q * v) % 3;
                    s += f[idx[p][q]] * ((m == 0) ? 1.0f : -0.5f);
                }
            }
            Kk[u][v] = s * (1.0f / 9.0f);
        }
    }
#pragma unroll
    for (int a = 0; a < 3; ++a) {
#pragma unroll
        for (int b = 0; b < 3; ++b) {
            const int m = (a * 3 + b) * 64 + o;
#pragma unroll
            for (int al = 0; al < 3; ++al) {
#pragma unroll
                for (int be = 0; be < 3; ++be) {
                    const int kh = (al - a + 4) % 3;
                    const int kw = (be - b + 4) % 3;
                    const unsigned short bf = f2bf(Kk[kh][kw]);
                    const int kap = (al * 3 + be) * 64 + i;
                    WtOld[m * 576 + kap] = bf;
                    const int MF = m >> 4, lmx = m & 15;
                    const int cc = kap >> 5, lgx = (kap >> 3) & 3, j = kap & 7;
                    Wtf[MF * 9216 + cc * 512 + (lgx * 16 + lmx) * 8 + j] = bf;
                }
            }
        }
    }
}

// ---------------------------------------------------------------------------
// gemm4: LDS double-buffered. (Unchanged from round 4, validated.)
// ---------------------------------------------------------------------------
__global__ __launch_bounds__(256, 2) void gemm4_kernel(
    const unsigned short* __restrict__ xT, const unsigned short* __restrict__ Wtf,
    const float* __restrict__ bias, float* __restrict__ out) {
    __shared__ __align__(16) char smem[81920];
    const int t = threadIdx.x;
    const int lane = t & 63;
    const int wv = t >> 6;
    const int wm = wv >> 1;
    const int wp = wv & 1;
    const int lm = lane & 15;
    const int lg = lane >> 4;

    const int orig = blockIdx.x;
    const int swz = (orig & 7) * 192 + (orig >> 3);
    const int mg = swz % 3;
    const int panel = swz / 3;
    const int n = panel >> 5;
    const int h0b = (panel & 31) * 2;

    f32x4 acc[6][4] = {};

#define STAGE(BUF, KC)                                                          \
    {                                                                           \
        const int al_ = (KC) / 3, be_ = (KC) - 3 * ((KC) / 3);                  \
        _Pragma("unroll") for (int it = 0; it < 10; ++it) {                     \
            char* ldsb = smem + (BUF) * 40960 + it * 4096 + wv * 1024;          \
            const unsigned short* src;                                          \
            if (it < 6) {                                                       \
                const int e = it * 2048 + t * 8;                                \
                const int mfL = e >> 10;                                        \
                const int rem = e & 1023;                                       \
                src = Wtf + (mg * 12 + mfL) * 9216 + (KC) * 1024 + rem;         \
            } else {                                                            \
                const int e = (it - 6) * 2048 + t * 8;                          \
                const int ccL = e >> 12;                                        \
                const int rem = e & 4095;                                       \
                const int p_ = rem >> 5;                                        \
                const int c_ = rem & 31;                                        \
                const int h_ = h0b + (p_ >> 6) + 64 * al_;                      \
                const int w_ = be_ * 64 + (p_ & 63);                            \
                src = xT + ((size_t)((n * 192 + h_) * 2 + ccL)) * 6144 +        \
                      w_ * 32 + c_;                                             \
            }                                                                   \
            gload16(src, ldsb);                                                 \
        }                                                                       \
    }

#define COMPUTE(BUF)                                                            \
    {                                                                           \
        const char* base = smem + (BUF) * 40960;                                \
        short8 af[12];                                                          \
        short8 bf[8];                                                           \
        _Pragma("unroll") for (int mf = 0; mf < 6; ++mf)                        \
            _Pragma("unroll") for (int cl = 0; cl < 2; ++cl)                    \
                af[mf * 2 + cl] = *(const short8*)(                             \
                    base + (wm * 6 + mf) * 2048 + cl * 1024 + lane * 16);       \
        _Pragma("unroll") for (int pf = 0; pf < 4; ++pf)                        \
            _Pragma("unroll") for (int cl = 0; cl < 2; ++cl)                    \
                bf[pf * 2 + cl] = *(const short8*)(                             \
                    base + 24576 + cl * 8192 +                                  \
                    (wp * 64 + pf * 16 + lm) * 64 + lg * 16);                   \
        _Pragma("unroll") for (int cl = 0; cl < 2; ++cl)                        \
            _Pragma("unroll") for (int mf = 0; mf < 6; ++mf)                    \
                _Pragma("unroll") for (int pf = 0; pf < 4; ++pf)                \
                    acc[mf][pf] = __builtin_amdgcn_mfma_f32_16x16x32_bf16(      \
                        af[mf * 2 + cl], bf[pf * 2 + cl], acc[mf][pf], 0, 0, 0);\
    }

    STAGE(0, 0);
    __syncthreads();
#pragma unroll
    for (int kc = 0; kc < 9; ++kc) {
        const int b = kc & 1;
        if (kc < 8) STAGE(b ^ 1, kc + 1);
        COMPUTE(b);
        if (kc < 8) __syncthreads();
    }
#undef STAGE
#undef COMPUTE

    const int h0 = h0b + wp;
#pragma unroll
    for (int mf = 0; mf < 6; ++mf) {
#pragma unroll
        for (int r = 0; r < 4; ++r) {
            const int m = mg * 192 + wm * 96 + mf * 16 + lg * 4 + r;
            const int o = m & 63;
            const int ab2 = m >> 6;
            const float bo = bias[o];
            const int rowoff =
                ((n * 64 + o) * 192 + (h0 + 64 * (ab2 / 3))) * 192 + 64 * (ab2 % 3);
#pragma unroll
            for (int pf = 0; pf < 4; ++pf) {
                out[rowoff + pf * 16 + lm] = acc[mf][pf][r] + bo;
            }
        }
    }
}

// ---------------------------------------------------------------------------
// Fallback GEMM (round-1 validated, LDS-staged fp32) if ws too small for xT.
// ---------------------------------------------------------------------------
__global__ __launch_bounds__(256) void gemm_fallback(const float* __restrict__ x,
                                                     const unsigned short* __restrict__ Wt,
                                                     const float* __restrict__ bias,
                                                     float* __restrict__ out) {
    __shared__ unsigned short Xs[64][36];
    const int t = threadIdx.x;
    const int lane = t & 63;
    const int wv = t >> 6;
    const int pblk = blockIdx.x;
    const int mg = blockIdx.y;
    const int n = pblk >> 6;
    const int h0 = pblk & 63;
    const int wave_m0 = mg * 192 + wv * 48;
    const int lm = lane & 15;
    const int lg = lane >> 4;

    f32x4 acc[3][4] = {};
    const float* xb = x + n * 64 * 36864;
    const int w0s = t & 63;
    const int kq = (t >> 6) * 8;

    for (int c = 0; c < 18; ++c) {
        const int ab = c >> 1;
        const int al = ab / 3;
        const int be = ab % 3;
        const int ih = (c & 1) * 32;
        const int base = ih * 36864 + (h0 + 64 * al) * 192 + 64 * be + w0s;
#pragma unroll
        for (int s = 0; s < 8; ++s) {
            const int kp = kq + s;
            Xs[w0s][kp] = f2bf(xb[base + kp * 36864]);
        }
        __syncthreads();
        const int kb = c * 32 + lg * 8;
        short8 af[3];
#pragma unroll
        for (int mf = 0; mf < 3; ++mf)
            af[mf] = *(const short8*)(Wt + (wave_m0 + mf * 16 + lm) * 576 + kb);
        short8 bf[4];
#pragma unroll
        for (int pf = 0; pf < 4; ++pf) {
            union { short8 v; unsigned long long q[2]; } u;
            const unsigned long long* s8 =
                (const unsigned long long*)(&Xs[pf * 16 + lm][lg * 8]);
            u.q[0] = s8[0];
            u.q[1] = s8[1];
            bf[pf] = u.v;
        }
#pragma unroll
        for (int mf = 0; mf < 3; ++mf)
#pragma unroll
            for (int pf = 0; pf < 4; ++pf)
                acc[mf][pf] = __builtin_amdgcn_mfma_f32_16x16x32_bf16(
                    af[mf], bf[pf], acc[mf][pf], 0, 0, 0);
        __syncthreads();
    }

#pragma unroll
    for (int mf = 0; mf < 3; ++mf)
#pragma unroll
        for (int r = 0; r < 4; ++r) {
            const int m = wave_m0 + mf * 16 + lg * 4 + r;
            const int o = m & 63;
            const int ab2 = m >> 6;
            const float bo = bias[o];
            const int rowoff =
                ((n * 64 + o) * 192 + (h0 + 64 * (ab2 / 3))) * 192 + 64 * (ab2 % 3);
#pragma unroll
            for (int pf = 0; pf < 4; ++pf)
                out[rowoff + pf * 16 + lm] = acc[mf][pf][r] + bo;
        }
}

// ---------------------------------------------------------------------------
extern "C" void kernel_launch(void* const* d_in, const int* in_sizes, int n_in,
                              void* d_out, int out_size, void* d_ws, size_t ws_size,
                              hipStream_t stream) {
    (void)in_sizes; (void)n_in; (void)out_size;
    const float* x = (const float*)d_in[0];
    const float* W = (const float*)d_in[1];
    const float* bias = (const float*)d_in[2];
    const float* u0 = (const float*)d_in[3];
    float* out = (float*)d_out;

    float* Fm = (float*)d_ws;
    unsigned short* Wtf = (unsigned short*)((char*)d_ws + WTF_OFF);
    unsigned short* WtOld = (unsigned short*)((char*)d_ws + WTOLD_OFF);
    unsigned short* xT = (unsigned short*)((char*)d_ws + XT_OFF);

    const bool big_ws = (ws_size >= WS_NEEDED);

    if (big_ws) {
        fmconv_kernel<<<5 + 1536, 512, 0, stream>>>(W, u0, x, Fm, xT);
        wbuild_kernel<<<16, 256, 0, stream>>>(Fm, Wtf, WtOld);
        gemm4_kernel<<<1536, 256, 0, stream>>>(xT, Wtf, bias, out);
    } else {
        fmconv_kernel<<<5, 512, 0, stream>>>(W, u0, x, Fm, xT);
        wbuild_kernel<<<16, 256, 0, stream>>>(Fm, Wtf, WtOld);
        dim3 g(1024, 3, 1);
        gemm_fallback<<<g, 256, 0, stream>>>(x, WtOld, bias, out);
    }
}